// Round 4
// baseline (6946.535 us; speedup 1.0000x reference)
//
#include <hip/hip_runtime.h>
#include <hip/hip_bf16.h>

#define N_USER 60000
#define N_ITEM 120000
#define NTOT   180000
#define NNZ_ADJ 3600000
#define NNZ_UG   960000
#define NNZ_IG  1920000

#define RPB    128          // rows per bin (LDS accumulator)
#define NB_ADJ ((NTOT  + RPB - 1) / RPB)   // 1407
#define NB_UG  ((N_USER+ RPB - 1) / RPB)   // 469
#define NB_IG  ((N_ITEM+ RPB - 1) / RPB)   // 938
#define NBMAX  1536
#define CHUNK  16384

typedef __hip_bfloat16 bf16;

// load float element i from input tensor of unknown dtype: flag=1 -> fp32, 0 -> bf16
__device__ __forceinline__ float ldf(const void* p, long i, int f) {
    return f ? ((const float*)p)[i] : __bfloat162float(((const bf16*)p)[i]);
}

// ---------------- dtype detector (adj_vals >= 0 -> bf16 words have bit15==0) ----
__global__ void k_detect(const void* __restrict__ vals, int* __restrict__ flag) {
    if (threadIdx.x == 0 && blockIdx.x == 0) {
        const unsigned short* w = (const unsigned short*)vals;
        int cnt = 0;
        for (int i = 0; i < 512; i += 2) cnt += (w[i] >> 15) & 1;
        *flag = (cnt > 16) ? 1 : 0;
    }
}

// ---------------- cast user/item emb -> ego0 (fp32) ----------------
__global__ __launch_bounds__(256) void k_cast2f32(const void* __restrict__ ue,
                                                  const void* __restrict__ ie,
                                                  float* __restrict__ ego,
                                                  const int* __restrict__ flag) {
    int f = *flag;
    long i = (long)blockIdx.x * 256 + threadIdx.x;   // NTOT*64 = 11,520,000
    const long uN = (long)N_USER * 64;
    if (i < (long)NTOT * 64) {
        ego[i] = (i < uN) ? ldf(ue, i, f) : ldf(ie, i - uN, f);
    }
}

// ================= binned edge-list build =================
// chunked LDS histogram of bin = row>>7
__global__ __launch_bounds__(256) void k_count_bin(const int* __restrict__ rows,
                                                   int* __restrict__ bincnt,
                                                   int nnz, int nb) {
    __shared__ int h[NBMAX];
    int t = threadIdx.x;
    long base = (long)blockIdx.x * CHUNK;
    for (int i = t; i < nb; i += 256) h[i] = 0;
    __syncthreads();
    for (int k = 0; k < CHUNK / 256; k++) {
        long e = base + k * 256 + t;
        if (e < nnz) atomicAdd(&h[rows[e] >> 7], 1);
    }
    __syncthreads();
    for (int i = t; i < nb; i += 256) {
        int c = h[i];
        if (c) atomicAdd(&bincnt[i], c);
    }
}

// single-block exclusive scan over <=NBMAX bins -> binptr, binpos
__global__ __launch_bounds__(1024) void k_scanbins(const int* __restrict__ cnt,
                                                   int* __restrict__ ptr,
                                                   int* __restrict__ pos,
                                                   int nb, int nnz) {
    __shared__ int s[1024];
    __shared__ int carry;
    int t = threadIdx.x;
    if (t == 0) carry = 0;
    __syncthreads();
    for (int base = 0; base < nb; base += 1024) {
        int i = base + t;
        int v = (i < nb) ? cnt[i] : 0;
        s[t] = v;
        __syncthreads();
        for (int d = 1; d < 1024; d <<= 1) {
            int w = (t >= d) ? s[t - d] : 0;
            __syncthreads();
            if (t >= d) s[t] += w;
            __syncthreads();
        }
        int ex = carry + s[t] - v;
        if (i < nb) { ptr[i] = ex; pos[i] = ex; }
        __syncthreads();
        if (t == 1023) carry += s[1023];
        __syncthreads();
    }
    if (t == 0) ptr[nb] = nnz;
}

// chunked scatter with per-block bulk reservation; packs {rl|col, val_f32}
__global__ __launch_bounds__(256) void k_scatter_bin(const int* __restrict__ rows,
                                                     const int* __restrict__ cols,
                                                     const void* __restrict__ vals,
                                                     uint2* __restrict__ rec,
                                                     int* __restrict__ binpos,
                                                     int nnz, int nb,
                                                     const int* __restrict__ flag) {
    __shared__ int lcnt[NBMAX];
    __shared__ int lbase[NBMAX];
    int f = *flag;
    int t = threadIdx.x;
    long base = (long)blockIdx.x * CHUNK;
    for (int i = t; i < nb; i += 256) lcnt[i] = 0;
    __syncthreads();
    for (int k = 0; k < CHUNK / 256; k++) {
        long e = base + k * 256 + t;
        if (e < nnz) atomicAdd(&lcnt[rows[e] >> 7], 1);
    }
    __syncthreads();
    for (int i = t; i < nb; i += 256) {
        int c = lcnt[i];
        lbase[i] = c ? atomicAdd(&binpos[i], c) : 0;
    }
    __syncthreads();
    for (int i = t; i < nb; i += 256) lcnt[i] = 0;
    __syncthreads();
    for (int k = 0; k < CHUNK / 256; k++) {
        long e = base + k * 256 + t;
        if (e < nnz) {
            int r = rows[e];
            int bin = r >> 7;
            int o = atomicAdd(&lcnt[bin], 1);
            unsigned meta = ((unsigned)(r & 127) << 24) | (unsigned)cols[e];
            float v = ldf(vals, e, f);
            rec[lbase[bin] + o] = make_uint2(meta, __float_as_uint(v));
        }
    }
}

// ================= binned SpMM: one 128-row bin per block, LDS accumulator ====
__global__ __launch_bounds__(256) void k_spmm_bin(const int* __restrict__ binptr,
                                                  const uint2* __restrict__ rec,
                                                  const float* __restrict__ x,
                                                  float* __restrict__ out,
                                                  int n_rows) {
    __shared__ float acc[RPB * 65];      // stride 65: spread banks across rows
    int t = threadIdx.x;
    for (int i = t; i < RPB * 65; i += 256) acc[i] = 0.0f;
    __syncthreads();
    int b = blockIdx.x;
    int s = binptr[b], e = binptr[b + 1];
    int p = t & 15;
    for (int j = s + (t >> 4); j < e; j += 16) {
        uint2 r = rec[j];
        int col = r.x & 0xFFFFFF;
        int rl  = r.x >> 24;
        float v = __uint_as_float(r.y);
        const float4 xv = *(const float4*)(x + (long)col * 64 + p * 4);
        float* a = acc + rl * 65 + p * 4;
        atomicAdd(a + 0, v * xv.x);
        atomicAdd(a + 1, v * xv.y);
        atomicAdd(a + 2, v * xv.z);
        atomicAdd(a + 3, v * xv.w);
    }
    __syncthreads();
    int row0 = b * RPB;
    for (int i = t; i < RPB * 64; i += 256) {
        int rl = i >> 6, j = i & 63;
        int row = row0 + rl;
        if (row < n_rows) out[(long)row * 64 + j] = acc[rl * 65 + j];
    }
}

// ---------------- Y[M,64] = act(X[M,64] @ W[64,64] + b) ----------------
// ACT: 1 = elu (f32 out), 2 = relu -> bf16 out (internal scratch)
template <int ACT>
__global__ __launch_bounds__(256) void k_gemm64(const float* __restrict__ X,
                                                const void* __restrict__ W,
                                                const void* __restrict__ b,
                                                void* __restrict__ Y, int M,
                                                const int* __restrict__ flag) {
    __shared__ float Wl[64][64];
    __shared__ float bl[64];
    int f = *flag;
    int tid = threadIdx.x;
    for (int i = tid; i < 4096; i += 256) Wl[i >> 6][i & 63] = ldf(W, i, f);
    if (tid < 64) bl[tid] = ldf(b, tid, f);
    __syncthreads();

    int r = blockIdx.x * 256 + tid;
    if (r >= M) return;
    const float* xr = X + (long)r * 64;

    float acc[64];
#pragma unroll
    for (int j = 0; j < 64; j++) acc[j] = bl[j];

    for (int k4 = 0; k4 < 64; k4 += 4) {
        float4 xv = *(const float4*)(xr + k4);
#pragma unroll
        for (int kk = 0; kk < 4; kk++) {
            float xs = (kk == 0) ? xv.x : (kk == 1) ? xv.y : (kk == 2) ? xv.z : xv.w;
#pragma unroll
            for (int j = 0; j < 64; j += 4) {
                float4 w4 = *(const float4*)&Wl[k4 + kk][j];
                acc[j + 0] += xs * w4.x;
                acc[j + 1] += xs * w4.y;
                acc[j + 2] += xs * w4.z;
                acc[j + 3] += xs * w4.w;
            }
        }
    }

    if (ACT == 2) {
        bf16* y = (bf16*)Y + (long)r * 64;
#pragma unroll
        for (int j = 0; j < 64; j++) y[j] = __float2bfloat16(fmaxf(acc[j], 0.0f));
    } else {
        float* y = (float*)Y + (long)r * 64;
#pragma unroll
        for (int j = 0; j < 64; j++) {
            float v = acc[j];
            y[j] = (v > 0.0f) ? v : (expf(v) - 1.0f);
        }
    }
}

// ---------------- fused NGCF layer transform + l2norm, ego updated IN PLACE ----
__global__ __launch_bounds__(256) void k_layer(const float* __restrict__ S,
                                               float* __restrict__ E,
                                               const void* __restrict__ Wgc,
                                               const void* __restrict__ bgc,
                                               const void* __restrict__ Wbi,
                                               const void* __restrict__ bbi,
                                               long woff, long boff,
                                               bf16* __restrict__ nm, int M,
                                               const int* __restrict__ flag) {
    __shared__ float W1[64][64];
    __shared__ float W2[64][64];
    __shared__ float bl[64];
    int f = *flag;
    int tid = threadIdx.x;
    for (int i = tid; i < 4096; i += 256) {
        W1[i >> 6][i & 63] = ldf(Wgc, woff + i, f);
        W2[i >> 6][i & 63] = ldf(Wbi, woff + i, f);
    }
    if (tid < 64) bl[tid] = ldf(bgc, boff + tid, f) + ldf(bbi, boff + tid, f);
    __syncthreads();

    int r = blockIdx.x * 256 + tid;
    if (r >= M) return;
    const float* sr = S + (long)r * 64;
    float* er = E + (long)r * 64;

    float acc[64];
#pragma unroll
    for (int j = 0; j < 64; j++) acc[j] = bl[j];

    for (int k4 = 0; k4 < 64; k4 += 4) {
        float4 sv = *(const float4*)(sr + k4);
        float4 ev = *(const float4*)(er + k4);
#pragma unroll
        for (int kk = 0; kk < 4; kk++) {
            float xs = (kk == 0) ? sv.x : (kk == 1) ? sv.y : (kk == 2) ? sv.z : sv.w;
            float xe = ((kk == 0) ? ev.x : (kk == 1) ? ev.y : (kk == 2) ? ev.z : ev.w) * xs;
#pragma unroll
            for (int j = 0; j < 64; j += 4) {
                float4 w1 = *(const float4*)&W1[k4 + kk][j];
                float4 w2 = *(const float4*)&W2[k4 + kk][j];
                acc[j + 0] += xs * w1.x + xe * w2.x;
                acc[j + 1] += xs * w1.y + xe * w2.y;
                acc[j + 2] += xs * w1.z + xe * w2.z;
                acc[j + 3] += xs * w1.w + xe * w2.w;
            }
        }
    }

    float ss = 0.0f;
#pragma unroll
    for (int j = 0; j < 64; j++) {
        float v = acc[j];
        v = (v > 0.0f) ? v : 0.2f * v;
        acc[j] = v;
        ss += v * v;
    }
    float sc = 1.0f / fmaxf(sqrtf(ss), 1e-12f);

    bf16* nr = nm + (long)r * 64;
#pragma unroll
    for (int j = 0; j < 64; j++) {
        er[j] = acc[j];
        nr[j] = __float2bfloat16(acc[j] * sc);
    }
}

// ---------------- final gather into output ----------------
__global__ __launch_bounds__(64) void k_gather(const int* __restrict__ users,
                                               const int* __restrict__ pos,
                                               const int* __restrict__ neg,
                                               const void* __restrict__ ue,
                                               const void* __restrict__ ie,
                                               const bf16* __restrict__ n1,
                                               const bf16* __restrict__ n2,
                                               const bf16* __restrict__ n3,
                                               const bf16* __restrict__ uh,
                                               const bf16* __restrict__ ih,
                                               void* __restrict__ out,
                                               const int* __restrict__ flag) {
    int f = *flag;
    int b = blockIdx.x;           // 0..12287: [users | pos | neg] x 4096
    int which = b >> 12;
    int s = b & 4095;
    int lane = threadIdx.x;       // 64
    long ebase, nbase;
    const void* e0;
    const bf16* hh;
    if (which == 0) {
        int r = users[s];
        e0 = ue; ebase = (long)r * 64;
        hh = uh + (long)r * 64;
        nbase = (long)r * 64;
    } else {
        int r = (which == 1) ? pos[s] : neg[s];
        e0 = ie; ebase = (long)r * 64;
        hh = ih + (long)r * 64;
        nbase = (long)(N_USER + r) * 64;
    }
    float o0 = ldf(e0, ebase + lane, f);
    float o1 = __bfloat162float(n1[nbase + lane]);
    float o2 = __bfloat162float(n2[nbase + lane]);
    float o3 = __bfloat162float(n3[nbase + lane]);
    float o4 = __bfloat162float(hh[lane]);
    long ob = (long)b * 320;
    if (f) {
        float* o = (float*)out + ob;
        o[lane] = o0; o[64 + lane] = o1; o[128 + lane] = o2;
        o[192 + lane] = o3; o[256 + lane] = o4;
    } else {
        bf16* o = (bf16*)out + ob;
        o[lane]       = __float2bfloat16(o0);
        o[64 + lane]  = __float2bfloat16(o1);
        o[128 + lane] = __float2bfloat16(o2);
        o[192 + lane] = __float2bfloat16(o3);
        o[256 + lane] = __float2bfloat16(o4);
    }
}

// host-side helper: build binned edge list for one graph
static void build_bins(const int* rows, const int* cols, const void* vals,
                       int nnz, int nb, int* bincnt, int* binpos, int* binptr,
                       uint2* rec, const int* FLAG, hipStream_t stream) {
    int nchunks = (nnz + CHUNK - 1) / CHUNK;
    hipMemsetAsync(bincnt, 0, (size_t)nb * 4, stream);
    k_count_bin<<<nchunks, 256, 0, stream>>>(rows, bincnt, nnz, nb);
    k_scanbins<<<1, 1024, 0, stream>>>(bincnt, binptr, binpos, nb, nnz);
    k_scatter_bin<<<nchunks, 256, 0, stream>>>(rows, cols, vals, rec, binpos, nnz, nb, FLAG);
}

extern "C" void kernel_launch(void* const* d_in, const int* in_sizes, int n_in,
                              void* d_out, int out_size, void* d_ws, size_t ws_size,
                              hipStream_t stream) {
    const int* users = (const int*)d_in[0];
    const int* pos   = (const int*)d_in[1];
    const int* neg   = (const int*)d_in[2];
    const int* adj_r = (const int*)d_in[3];
    const int* adj_c = (const int*)d_in[4];
    const void* adj_v = d_in[5];
    const int* ug_r  = (const int*)d_in[6];
    const int* ug_c  = (const int*)d_in[7];
    const void* ug_v = d_in[8];
    const int* ig_r  = (const int*)d_in[9];
    const int* ig_c  = (const int*)d_in[10];
    const void* ig_v = d_in[11];
    const void* ue   = d_in[12];
    const void* ie   = d_in[13];
    const void* Wgc  = d_in[14];
    const void* bgc  = d_in[15];
    const void* Wbi  = d_in[16];
    const void* bbi  = d_in[17];
    const void* Wu0  = d_in[18];
    const void* bu0  = d_in[19];
    const void* Wu1  = d_in[20];
    const void* bu1  = d_in[21];
    const void* Wi0  = d_in[22];
    const void* bi0  = d_in[23];
    const void* Wi1  = d_in[24];
    const void* bi1  = d_in[25];

    char* ws = (char*)d_ws;
    int*   FLAG = (int*)(ws + 0);                        // 256 B
    float* egoA = (float*)(ws + 256);                    // 46,080,000
    float* T1   = (float*)(ws + 46080256L);              // 46,080,000
    bf16*  UH   = (bf16*)(ws + 92160256L);               //  7,680,000
    bf16*  IH   = (bf16*)(ws + 99840256L);               // 15,360,000
    bf16*  NM1  = (bf16*)(ws + 115200256L);              // 23,040,000
    bf16*  NM2  = (bf16*)(ws + 138240256L);              // 23,040,000
    bf16*  NM3  = (bf16*)(ws + 161280256L);              // 23,040,000
    // T2 aliases NM2..NM3 (T2 dead before layer 2 writes NM2)
    float* T2   = (float*)(ws + 138240256L);             // 30,720,000 (alias)
    uint2* recA = (uint2*)(ws + 184320256L);             // 28,800,000
    uint2* recU = (uint2*)(ws + 213120256L);             //  7,680,000
    uint2* recI = (uint2*)(ws + 220800256L);             // 15,360,000
    int* binptrA = (int*)(ws + 236160256L);              // 5,632
    int* binptrU = (int*)(ws + 236165888L);              // 2,048
    int* binptrI = (int*)(ws + 236167936L);              // 4,096
    int* bincnt  = (int*)(ws + 236172032L);              // 6,144 (shared scratch)
    int* binpos  = (int*)(ws + 236178176L);              // 6,144
                                                         // end ~236.2 MB (< 261 MB proven)

    k_detect<<<1, 64, 0, stream>>>(adj_v, FLAG);
    k_cast2f32<<<45000, 256, 0, stream>>>(ue, ie, egoA, FLAG);

    // ---- build binned edge lists ----
    build_bins(ug_r,  ug_c,  ug_v,  NNZ_UG,  NB_UG,  bincnt, binpos, binptrU, recU, FLAG, stream);
    build_bins(ig_r,  ig_c,  ig_v,  NNZ_IG,  NB_IG,  bincnt, binpos, binptrI, recI, FLAG, stream);
    build_bins(adj_r, adj_c, adj_v, NNZ_ADJ, NB_ADJ, bincnt, binpos, binptrA, recA, FLAG, stream);

    // ---- user MLP branch ----
    k_spmm_bin<<<NB_UG, 256, 0, stream>>>(binptrU, recU, egoA, T1, N_USER);
    k_gemm64<1><<<(N_USER + 255) / 256, 256, 0, stream>>>(T1, Wu0, bu0, T2, N_USER, FLAG);
    k_spmm_bin<<<NB_UG, 256, 0, stream>>>(binptrU, recU, T2, T1, N_USER);
    k_gemm64<2><<<(N_USER + 255) / 256, 256, 0, stream>>>(T1, Wu1, bu1, UH, N_USER, FLAG);

    // ---- item MLP branch ----
    const float* egoI = egoA + (size_t)N_USER * 64;
    k_spmm_bin<<<NB_IG, 256, 0, stream>>>(binptrI, recI, egoI, T1, N_ITEM);
    k_gemm64<1><<<(N_ITEM + 255) / 256, 256, 0, stream>>>(T1, Wi0, bi0, T2, N_ITEM, FLAG);
    k_spmm_bin<<<NB_IG, 256, 0, stream>>>(binptrI, recI, T2, T1, N_ITEM);
    k_gemm64<2><<<(N_ITEM + 255) / 256, 256, 0, stream>>>(T1, Wi1, bi1, IH, N_ITEM, FLAG);

    // ---- 3 NGCF layers (ego updated in place; norm fused) ----
    bf16* norms[3] = {NM1, NM2, NM3};
    for (int k = 0; k < 3; k++) {
        k_spmm_bin<<<NB_ADJ, 256, 0, stream>>>(binptrA, recA, egoA, T1, NTOT);
        k_layer<<<(NTOT + 255) / 256, 256, 0, stream>>>(T1, egoA, Wgc, bgc, Wbi, bbi,
                                                        (long)k * 4096, (long)k * 64,
                                                        norms[k], NTOT, FLAG);
    }

    // ---- output gather ----
    k_gather<<<12288, 64, 0, stream>>>(users, pos, neg, ue, ie, NM1, NM2, NM3, UH, IH,
                                       d_out, FLAG);
}

// Round 5
// 1836.790 us; speedup vs baseline: 3.7819x; 3.7819x over previous
//
#include <hip/hip_runtime.h>
#include <hip/hip_bf16.h>

#define N_USER 60000
#define N_ITEM 120000
#define NTOT   180000
#define NNZ_ADJ 3600000
#define NNZ_UG   960000
#define NNZ_IG  1920000

#define RPB    128          // rows per bin
#define NB_ADJ ((NTOT  + RPB - 1) / RPB)   // 1407
#define NB_UG  ((N_USER+ RPB - 1) / RPB)   // 469
#define NB_IG  ((N_ITEM+ RPB - 1) / RPB)   // 938
#define NBMAX  1536
#define CHUNK  16384

typedef __hip_bfloat16 bf16;

// load float element i from input tensor of unknown dtype: flag=1 -> fp32, 0 -> bf16
__device__ __forceinline__ float ldf(const void* p, long i, int f) {
    return f ? ((const float*)p)[i] : __bfloat162float(((const bf16*)p)[i]);
}

// ---------------- dtype detector (adj_vals >= 0 -> bf16 words have bit15==0) ----
__global__ void k_detect(const void* __restrict__ vals, int* __restrict__ flag) {
    if (threadIdx.x == 0 && blockIdx.x == 0) {
        const unsigned short* w = (const unsigned short*)vals;
        int cnt = 0;
        for (int i = 0; i < 512; i += 2) cnt += (w[i] >> 15) & 1;
        *flag = (cnt > 16) ? 1 : 0;
    }
}

// ---------------- cast user/item emb -> ego0 (fp32) ----------------
__global__ __launch_bounds__(256) void k_cast2f32(const void* __restrict__ ue,
                                                  const void* __restrict__ ie,
                                                  float* __restrict__ ego,
                                                  const int* __restrict__ flag) {
    int f = *flag;
    long i = (long)blockIdx.x * 256 + threadIdx.x;   // NTOT*64 = 11,520,000
    const long uN = (long)N_USER * 64;
    if (i < (long)NTOT * 64) {
        ego[i] = (i < uN) ? ldf(ue, i, f) : ldf(ie, i - uN, f);
    }
}

// ================= binned edge-list build =================
__global__ __launch_bounds__(256) void k_count_bin(const int* __restrict__ rows,
                                                   int* __restrict__ bincnt,
                                                   int nnz, int nb) {
    __shared__ int h[NBMAX];
    int t = threadIdx.x;
    long base = (long)blockIdx.x * CHUNK;
    for (int i = t; i < nb; i += 256) h[i] = 0;
    __syncthreads();
    for (int k = 0; k < CHUNK / 256; k++) {
        long e = base + k * 256 + t;
        if (e < nnz) atomicAdd(&h[rows[e] >> 7], 1);
    }
    __syncthreads();
    for (int i = t; i < nb; i += 256) {
        int c = h[i];
        if (c) atomicAdd(&bincnt[i], c);
    }
}

__global__ __launch_bounds__(1024) void k_scanbins(const int* __restrict__ cnt,
                                                   int* __restrict__ ptr,
                                                   int* __restrict__ pos,
                                                   int nb, int nnz) {
    __shared__ int s[1024];
    __shared__ int carry;
    int t = threadIdx.x;
    if (t == 0) carry = 0;
    __syncthreads();
    for (int base = 0; base < nb; base += 1024) {
        int i = base + t;
        int v = (i < nb) ? cnt[i] : 0;
        s[t] = v;
        __syncthreads();
        for (int d = 1; d < 1024; d <<= 1) {
            int w = (t >= d) ? s[t - d] : 0;
            __syncthreads();
            if (t >= d) s[t] += w;
            __syncthreads();
        }
        int ex = carry + s[t] - v;
        if (i < nb) { ptr[i] = ex; pos[i] = ex; }
        __syncthreads();
        if (t == 1023) carry += s[1023];
        __syncthreads();
    }
    if (t == 0) ptr[nb] = nnz;
}

// chunked scatter with per-block bulk reservation; packs {rl|col, val_f32}
__global__ __launch_bounds__(256) void k_scatter_bin(const int* __restrict__ rows,
                                                     const int* __restrict__ cols,
                                                     const void* __restrict__ vals,
                                                     uint2* __restrict__ rec,
                                                     int* __restrict__ binpos,
                                                     int nnz, int nb,
                                                     const int* __restrict__ flag) {
    __shared__ int lcnt[NBMAX];
    __shared__ int lbase[NBMAX];
    int f = *flag;
    int t = threadIdx.x;
    long base = (long)blockIdx.x * CHUNK;
    for (int i = t; i < nb; i += 256) lcnt[i] = 0;
    __syncthreads();
    for (int k = 0; k < CHUNK / 256; k++) {
        long e = base + k * 256 + t;
        if (e < nnz) atomicAdd(&lcnt[rows[e] >> 7], 1);
    }
    __syncthreads();
    for (int i = t; i < nb; i += 256) {
        int c = lcnt[i];
        lbase[i] = c ? atomicAdd(&binpos[i], c) : 0;
    }
    __syncthreads();
    for (int i = t; i < nb; i += 256) lcnt[i] = 0;
    __syncthreads();
    for (int k = 0; k < CHUNK / 256; k++) {
        long e = base + k * 256 + t;
        if (e < nnz) {
            int r = rows[e];
            int bin = r >> 7;
            int o = atomicAdd(&lcnt[bin], 1);
            unsigned meta = ((unsigned)(r & 127) << 24) | (unsigned)cols[e];
            float v = ldf(vals, e, f);
            rec[lbase[bin] + o] = make_uint2(meta, __float_as_uint(v));
        }
    }
}

// ---------------- per-bin counting sort: bin-grouped rec -> row-sorted rec2 ----
// One block per bin. LDS 128-counter histogram + scan; emits rowptr and rec2
// (writes stay inside the bin's contiguous region -> L2-local).
__global__ __launch_bounds__(256) void k_sortbin(const int* __restrict__ binptr,
                                                 const uint2* __restrict__ rec,
                                                 uint2* __restrict__ rec2,
                                                 int* __restrict__ rowptr,
                                                 int n_rows, int nnz) {
    __shared__ int cnt[RPB];
    __shared__ int pos[RPB];
    int b = blockIdx.x, t = threadIdx.x;
    int s = binptr[b], e = binptr[b + 1];
    if (t < RPB) cnt[t] = 0;
    __syncthreads();
    for (int j = s + t; j < e; j += 256)
        atomicAdd(&cnt[rec[j].x >> 24], 1);
    __syncthreads();
    // Hillis-Steele inclusive scan over 128 counters
    if (t < RPB) pos[t] = cnt[t];
    __syncthreads();
    for (int d = 1; d < RPB; d <<= 1) {
        int v = (t < RPB && t >= d) ? pos[t - d] : 0;
        __syncthreads();
        if (t < RPB && t >= d) pos[t] += v;
        __syncthreads();
    }
    int ex = (t < RPB) ? (pos[t] - cnt[t]) : 0;   // exclusive
    __syncthreads();
    if (t < RPB) {
        pos[t] = ex;
        int row = b * RPB + t;
        if (row < n_rows) rowptr[row] = s + ex;
    }
    if (b == 0 && t == 0) rowptr[n_rows] = nnz;
    __syncthreads();
    for (int j = s + t; j < e; j += 256) {
        uint2 r = rec[j];
        int o = atomicAdd(&pos[r.x >> 24], 1);
        rec2[s + o] = r;
    }
}

// ================= CSR SpMM on packed records: one row per quarter-wave =======
__global__ __launch_bounds__(256) void k_spmm_csr2(const int* __restrict__ rowptr,
                                                   const uint2* __restrict__ rec,
                                                   const float* __restrict__ x,
                                                   float* __restrict__ out,
                                                   int n_rows) {
    int row = blockIdx.x * 16 + (threadIdx.x >> 4);
    int p = threadIdx.x & 15;
    if (row >= n_rows) return;
    int s = rowptr[row], e = rowptr[row + 1];
    float4 acc = {0.f, 0.f, 0.f, 0.f};
    for (int j = s; j < e; j++) {
        uint2 r = rec[j];
        int col = r.x & 0xFFFFFF;
        float v = __uint_as_float(r.y);
        const float4 xv = *(const float4*)(x + (long)col * 64 + p * 4);
        acc.x += v * xv.x;
        acc.y += v * xv.y;
        acc.z += v * xv.z;
        acc.w += v * xv.w;
    }
    *(float4*)(out + (long)row * 64 + p * 4) = acc;
}

// ---------------- Y[M,64] = act(X[M,64] @ W[64,64] + b) ----------------
// ACT: 1 = elu (f32 out), 2 = relu -> bf16 out (internal scratch)
template <int ACT>
__global__ __launch_bounds__(256) void k_gemm64(const float* __restrict__ X,
                                                const void* __restrict__ W,
                                                const void* __restrict__ b,
                                                void* __restrict__ Y, int M,
                                                const int* __restrict__ flag) {
    __shared__ float Wl[64][64];
    __shared__ float bl[64];
    int f = *flag;
    int tid = threadIdx.x;
    for (int i = tid; i < 4096; i += 256) Wl[i >> 6][i & 63] = ldf(W, i, f);
    if (tid < 64) bl[tid] = ldf(b, tid, f);
    __syncthreads();

    int r = blockIdx.x * 256 + tid;
    if (r >= M) return;
    const float* xr = X + (long)r * 64;

    float acc[64];
#pragma unroll
    for (int j = 0; j < 64; j++) acc[j] = bl[j];

    for (int k4 = 0; k4 < 64; k4 += 4) {
        float4 xv = *(const float4*)(xr + k4);
#pragma unroll
        for (int kk = 0; kk < 4; kk++) {
            float xs = (kk == 0) ? xv.x : (kk == 1) ? xv.y : (kk == 2) ? xv.z : xv.w;
#pragma unroll
            for (int j = 0; j < 64; j += 4) {
                float4 w4 = *(const float4*)&Wl[k4 + kk][j];
                acc[j + 0] += xs * w4.x;
                acc[j + 1] += xs * w4.y;
                acc[j + 2] += xs * w4.z;
                acc[j + 3] += xs * w4.w;
            }
        }
    }

    if (ACT == 2) {
        bf16* y = (bf16*)Y + (long)r * 64;
#pragma unroll
        for (int j = 0; j < 64; j++) y[j] = __float2bfloat16(fmaxf(acc[j], 0.0f));
    } else {
        float* y = (float*)Y + (long)r * 64;
#pragma unroll
        for (int j = 0; j < 64; j++) {
            float v = acc[j];
            y[j] = (v > 0.0f) ? v : (expf(v) - 1.0f);
        }
    }
}

// ---------------- fused NGCF layer transform + l2norm, ego updated IN PLACE ----
__global__ __launch_bounds__(256) void k_layer(const float* __restrict__ S,
                                               float* __restrict__ E,
                                               const void* __restrict__ Wgc,
                                               const void* __restrict__ bgc,
                                               const void* __restrict__ Wbi,
                                               const void* __restrict__ bbi,
                                               long woff, long boff,
                                               bf16* __restrict__ nm, int M,
                                               const int* __restrict__ flag) {
    __shared__ float W1[64][64];
    __shared__ float W2[64][64];
    __shared__ float bl[64];
    int f = *flag;
    int tid = threadIdx.x;
    for (int i = tid; i < 4096; i += 256) {
        W1[i >> 6][i & 63] = ldf(Wgc, woff + i, f);
        W2[i >> 6][i & 63] = ldf(Wbi, woff + i, f);
    }
    if (tid < 64) bl[tid] = ldf(bgc, boff + tid, f) + ldf(bbi, boff + tid, f);
    __syncthreads();

    int r = blockIdx.x * 256 + tid;
    if (r >= M) return;
    const float* sr = S + (long)r * 64;
    float* er = E + (long)r * 64;

    float acc[64];
#pragma unroll
    for (int j = 0; j < 64; j++) acc[j] = bl[j];

    for (int k4 = 0; k4 < 64; k4 += 4) {
        float4 sv = *(const float4*)(sr + k4);
        float4 ev = *(const float4*)(er + k4);
#pragma unroll
        for (int kk = 0; kk < 4; kk++) {
            float xs = (kk == 0) ? sv.x : (kk == 1) ? sv.y : (kk == 2) ? sv.z : sv.w;
            float xe = ((kk == 0) ? ev.x : (kk == 1) ? ev.y : (kk == 2) ? ev.z : ev.w) * xs;
#pragma unroll
            for (int j = 0; j < 64; j += 4) {
                float4 w1 = *(const float4*)&W1[k4 + kk][j];
                float4 w2 = *(const float4*)&W2[k4 + kk][j];
                acc[j + 0] += xs * w1.x + xe * w2.x;
                acc[j + 1] += xs * w1.y + xe * w2.y;
                acc[j + 2] += xs * w1.z + xe * w2.z;
                acc[j + 3] += xs * w1.w + xe * w2.w;
            }
        }
    }

    float ss = 0.0f;
#pragma unroll
    for (int j = 0; j < 64; j++) {
        float v = acc[j];
        v = (v > 0.0f) ? v : 0.2f * v;
        acc[j] = v;
        ss += v * v;
    }
    float sc = 1.0f / fmaxf(sqrtf(ss), 1e-12f);

    bf16* nr = nm + (long)r * 64;
#pragma unroll
    for (int j = 0; j < 64; j++) {
        er[j] = acc[j];
        nr[j] = __float2bfloat16(acc[j] * sc);
    }
}

// ---------------- final gather into output ----------------
__global__ __launch_bounds__(64) void k_gather(const int* __restrict__ users,
                                               const int* __restrict__ pos,
                                               const int* __restrict__ neg,
                                               const void* __restrict__ ue,
                                               const void* __restrict__ ie,
                                               const bf16* __restrict__ n1,
                                               const bf16* __restrict__ n2,
                                               const bf16* __restrict__ n3,
                                               const bf16* __restrict__ uh,
                                               const bf16* __restrict__ ih,
                                               void* __restrict__ out,
                                               const int* __restrict__ flag) {
    int f = *flag;
    int b = blockIdx.x;           // 0..12287: [users | pos | neg] x 4096
    int which = b >> 12;
    int s = b & 4095;
    int lane = threadIdx.x;       // 64
    long ebase, nbase;
    const void* e0;
    const bf16* hh;
    if (which == 0) {
        int r = users[s];
        e0 = ue; ebase = (long)r * 64;
        hh = uh + (long)r * 64;
        nbase = (long)r * 64;
    } else {
        int r = (which == 1) ? pos[s] : neg[s];
        e0 = ie; ebase = (long)r * 64;
        hh = ih + (long)r * 64;
        nbase = (long)(N_USER + r) * 64;
    }
    float o0 = ldf(e0, ebase + lane, f);
    float o1 = __bfloat162float(n1[nbase + lane]);
    float o2 = __bfloat162float(n2[nbase + lane]);
    float o3 = __bfloat162float(n3[nbase + lane]);
    float o4 = __bfloat162float(hh[lane]);
    long ob = (long)b * 320;
    if (f) {
        float* o = (float*)out + ob;
        o[lane] = o0; o[64 + lane] = o1; o[128 + lane] = o2;
        o[192 + lane] = o3; o[256 + lane] = o4;
    } else {
        bf16* o = (bf16*)out + ob;
        o[lane]       = __float2bfloat16(o0);
        o[64 + lane]  = __float2bfloat16(o1);
        o[128 + lane] = __float2bfloat16(o2);
        o[192 + lane] = __float2bfloat16(o3);
        o[256 + lane] = __float2bfloat16(o4);
    }
}

// host-side helper: build row-sorted packed CSR for one graph
static void build_graph(const int* rows, const int* cols, const void* vals,
                        int nnz, int nb, int n_rows,
                        int* bincnt, int* binpos, int* binptr,
                        uint2* recTmp, uint2* rec2, int* rowptr,
                        const int* FLAG, hipStream_t stream) {
    int nchunks = (nnz + CHUNK - 1) / CHUNK;
    hipMemsetAsync(bincnt, 0, (size_t)nb * 4, stream);
    k_count_bin<<<nchunks, 256, 0, stream>>>(rows, bincnt, nnz, nb);
    k_scanbins<<<1, 1024, 0, stream>>>(bincnt, binptr, binpos, nb, nnz);
    k_scatter_bin<<<nchunks, 256, 0, stream>>>(rows, cols, vals, recTmp, binpos, nnz, nb, FLAG);
    k_sortbin<<<nb, 256, 0, stream>>>(binptr, recTmp, rec2, rowptr, n_rows, nnz);
}

extern "C" void kernel_launch(void* const* d_in, const int* in_sizes, int n_in,
                              void* d_out, int out_size, void* d_ws, size_t ws_size,
                              hipStream_t stream) {
    const int* users = (const int*)d_in[0];
    const int* pos   = (const int*)d_in[1];
    const int* neg   = (const int*)d_in[2];
    const int* adj_r = (const int*)d_in[3];
    const int* adj_c = (const int*)d_in[4];
    const void* adj_v = d_in[5];
    const int* ug_r  = (const int*)d_in[6];
    const int* ug_c  = (const int*)d_in[7];
    const void* ug_v = d_in[8];
    const int* ig_r  = (const int*)d_in[9];
    const int* ig_c  = (const int*)d_in[10];
    const void* ig_v = d_in[11];
    const void* ue   = d_in[12];
    const void* ie   = d_in[13];
    const void* Wgc  = d_in[14];
    const void* bgc  = d_in[15];
    const void* Wbi  = d_in[16];
    const void* bbi  = d_in[17];
    const void* Wu0  = d_in[18];
    const void* bu0  = d_in[19];
    const void* Wu1  = d_in[20];
    const void* bu1  = d_in[21];
    const void* Wi0  = d_in[22];
    const void* bi0  = d_in[23];
    const void* Wi1  = d_in[24];
    const void* bi1  = d_in[25];

    char* ws = (char*)d_ws;
    int*   FLAG = (int*)(ws + 0);                        // 256 B
    float* egoA = (float*)(ws + 256);                    // 46,080,000
    float* T1   = (float*)(ws + 46080256L);              // 46,080,000
    bf16*  UH   = (bf16*)(ws + 92160256L);               //  7,680,000
    bf16*  IH   = (bf16*)(ws + 99840256L);               // 15,360,000
    bf16*  NM1  = (bf16*)(ws + 115200256L);              // 23,040,000
    bf16*  NM2  = (bf16*)(ws + 138240256L);              // 23,040,000
    bf16*  NM3  = (bf16*)(ws + 161280256L);              // 23,040,000
    // T2 aliases NM2..NM3 (T2 dead before layer 2 writes NM2)
    float* T2   = (float*)(ws + 138240256L);             // 30,720,000 (alias)
    // recTmp aliases T1 (builds finish before any SpMM writes T1)
    uint2* recTmp = (uint2*)(ws + 46080256L);            // 28,800,000 (alias)
    uint2* rec2A = (uint2*)(ws + 184320256L);            // 28,800,000
    uint2* rec2U = (uint2*)(ws + 213120256L);            //  7,680,000
    uint2* rec2I = (uint2*)(ws + 220800256L);            // 15,360,000
    int* rowptrA = (int*)(ws + 236160256L);              //    720,128
    int* rowptrU = (int*)(ws + 236880384L);              //    240,128
    int* rowptrI = (int*)(ws + 237120512L);              //    480,128
    int* binptr  = (int*)(ws + 237600640L);              //      6,400
    int* bincnt  = (int*)(ws + 237607040L);              //      6,144
    int* binpos  = (int*)(ws + 237613184L);              //      6,144
                                                         // end ~237.6 MB (< 261 MB proven)

    k_detect<<<1, 64, 0, stream>>>(adj_v, FLAG);
    k_cast2f32<<<45000, 256, 0, stream>>>(ue, ie, egoA, FLAG);

    // ---- build row-sorted packed CSR for the three graphs (recTmp aliases T1) ----
    build_graph(ug_r,  ug_c,  ug_v,  NNZ_UG,  NB_UG,  N_USER,
                bincnt, binpos, binptr, recTmp, rec2U, rowptrU, FLAG, stream);
    build_graph(ig_r,  ig_c,  ig_v,  NNZ_IG,  NB_IG,  N_ITEM,
                bincnt, binpos, binptr, recTmp, rec2I, rowptrI, FLAG, stream);
    build_graph(adj_r, adj_c, adj_v, NNZ_ADJ, NB_ADJ, NTOT,
                bincnt, binpos, binptr, recTmp, rec2A, rowptrA, FLAG, stream);

    // ---- user MLP branch ----
    k_spmm_csr2<<<(N_USER + 15) / 16, 256, 0, stream>>>(rowptrU, rec2U, egoA, T1, N_USER);
    k_gemm64<1><<<(N_USER + 255) / 256, 256, 0, stream>>>(T1, Wu0, bu0, T2, N_USER, FLAG);
    k_spmm_csr2<<<(N_USER + 15) / 16, 256, 0, stream>>>(rowptrU, rec2U, T2, T1, N_USER);
    k_gemm64<2><<<(N_USER + 255) / 256, 256, 0, stream>>>(T1, Wu1, bu1, UH, N_USER, FLAG);

    // ---- item MLP branch ----
    const float* egoI = egoA + (size_t)N_USER * 64;
    k_spmm_csr2<<<(N_ITEM + 15) / 16, 256, 0, stream>>>(rowptrI, rec2I, egoI, T1, N_ITEM);
    k_gemm64<1><<<(N_ITEM + 255) / 256, 256, 0, stream>>>(T1, Wi0, bi0, T2, N_ITEM, FLAG);
    k_spmm_csr2<<<(N_ITEM + 15) / 16, 256, 0, stream>>>(rowptrI, rec2I, T2, T1, N_ITEM);
    k_gemm64<2><<<(N_ITEM + 255) / 256, 256, 0, stream>>>(T1, Wi1, bi1, IH, N_ITEM, FLAG);

    // ---- 3 NGCF layers (ego updated in place; norm fused) ----
    bf16* norms[3] = {NM1, NM2, NM3};
    for (int k = 0; k < 3; k++) {
        k_spmm_csr2<<<(NTOT + 15) / 16, 256, 0, stream>>>(rowptrA, rec2A, egoA, T1, NTOT);
        k_layer<<<(NTOT + 255) / 256, 256, 0, stream>>>(T1, egoA, Wgc, bgc, Wbi, bbi,
                                                        (long)k * 4096, (long)k * 64,
                                                        norms[k], NTOT, FLAG);
    }

    // ---- output gather ----
    k_gather<<<12288, 64, 0, stream>>>(users, pos, neg, ue, ie, NM1, NM2, NM3, UH, IH,
                                       d_out, FLAG);
}

// Round 6
// 1587.691 us; speedup vs baseline: 4.3752x; 1.1569x over previous
//
#include <hip/hip_runtime.h>
#include <hip/hip_bf16.h>

#define N_USER 60000
#define N_ITEM 120000
#define NTOT   180000
#define NNZ_ADJ 3600000
#define NNZ_UG   960000
#define NNZ_IG  1920000

#define RPB    128          // rows per bin
#define NB_ADJ ((NTOT  + RPB - 1) / RPB)   // 1407
#define NB_UG  ((N_USER+ RPB - 1) / RPB)   // 469
#define NB_IG  ((N_ITEM+ RPB - 1) / RPB)   // 938
#define NBMAX  1536
#define CHUNK  16384

typedef __hip_bfloat16 bf16;

// load float element i from input tensor of unknown dtype: flag=1 -> fp32, 0 -> bf16
__device__ __forceinline__ float ldf(const void* p, long i, int f) {
    return f ? ((const float*)p)[i] : __bfloat162float(((const bf16*)p)[i]);
}

// ---------------- dtype detector (adj_vals >= 0 -> bf16 words have bit15==0) ----
__global__ void k_detect(const void* __restrict__ vals, int* __restrict__ flag) {
    if (threadIdx.x == 0 && blockIdx.x == 0) {
        const unsigned short* w = (const unsigned short*)vals;
        int cnt = 0;
        for (int i = 0; i < 512; i += 2) cnt += (w[i] >> 15) & 1;
        *flag = (cnt > 16) ? 1 : 0;
    }
}

// ---------------- cast user/item emb -> ego0 fp32 + bf16 copy ----------------
__global__ __launch_bounds__(256) void k_cast(const void* __restrict__ ue,
                                              const void* __restrict__ ie,
                                              float* __restrict__ ego,
                                              bf16* __restrict__ ego16,
                                              const int* __restrict__ flag) {
    int f = *flag;
    long i = (long)blockIdx.x * 256 + threadIdx.x;   // NTOT*64 = 11,520,000
    const long uN = (long)N_USER * 64;
    if (i < (long)NTOT * 64) {
        float v = (i < uN) ? ldf(ue, i, f) : ldf(ie, i - uN, f);
        ego[i] = v;
        ego16[i] = __float2bfloat16(v);
    }
}

// ================= binned edge-list build =================
__global__ __launch_bounds__(256) void k_count_bin(const int* __restrict__ rows,
                                                   int* __restrict__ bincnt,
                                                   int nnz, int nb) {
    __shared__ int h[NBMAX];
    int t = threadIdx.x;
    long base = (long)blockIdx.x * CHUNK;
    for (int i = t; i < nb; i += 256) h[i] = 0;
    __syncthreads();
    for (int k = 0; k < CHUNK / 256; k++) {
        long e = base + k * 256 + t;
        if (e < nnz) atomicAdd(&h[rows[e] >> 7], 1);
    }
    __syncthreads();
    for (int i = t; i < nb; i += 256) {
        int c = h[i];
        if (c) atomicAdd(&bincnt[i], c);
    }
}

__global__ __launch_bounds__(1024) void k_scanbins(const int* __restrict__ cnt,
                                                   int* __restrict__ ptr,
                                                   int* __restrict__ pos,
                                                   int nb, int nnz) {
    __shared__ int s[1024];
    __shared__ int carry;
    int t = threadIdx.x;
    if (t == 0) carry = 0;
    __syncthreads();
    for (int base = 0; base < nb; base += 1024) {
        int i = base + t;
        int v = (i < nb) ? cnt[i] : 0;
        s[t] = v;
        __syncthreads();
        for (int d = 1; d < 1024; d <<= 1) {
            int w = (t >= d) ? s[t - d] : 0;
            __syncthreads();
            if (t >= d) s[t] += w;
            __syncthreads();
        }
        int ex = carry + s[t] - v;
        if (i < nb) { ptr[i] = ex; pos[i] = ex; }
        __syncthreads();
        if (t == 1023) carry += s[1023];
        __syncthreads();
    }
    if (t == 0) ptr[nb] = nnz;
}

// chunked scatter with per-block bulk reservation; packs {rl|col, val_f32}
__global__ __launch_bounds__(256) void k_scatter_bin(const int* __restrict__ rows,
                                                     const int* __restrict__ cols,
                                                     const void* __restrict__ vals,
                                                     uint2* __restrict__ rec,
                                                     int* __restrict__ binpos,
                                                     int nnz, int nb,
                                                     const int* __restrict__ flag) {
    __shared__ int lcnt[NBMAX];
    __shared__ int lbase[NBMAX];
    int f = *flag;
    int t = threadIdx.x;
    long base = (long)blockIdx.x * CHUNK;
    for (int i = t; i < nb; i += 256) lcnt[i] = 0;
    __syncthreads();
    for (int k = 0; k < CHUNK / 256; k++) {
        long e = base + k * 256 + t;
        if (e < nnz) atomicAdd(&lcnt[rows[e] >> 7], 1);
    }
    __syncthreads();
    for (int i = t; i < nb; i += 256) {
        int c = lcnt[i];
        lbase[i] = c ? atomicAdd(&binpos[i], c) : 0;
    }
    __syncthreads();
    for (int i = t; i < nb; i += 256) lcnt[i] = 0;
    __syncthreads();
    for (int k = 0; k < CHUNK / 256; k++) {
        long e = base + k * 256 + t;
        if (e < nnz) {
            int r = rows[e];
            int bin = r >> 7;
            int o = atomicAdd(&lcnt[bin], 1);
            unsigned meta = ((unsigned)(r & 127) << 24) | (unsigned)cols[e];
            float v = ldf(vals, e, f);
            rec[lbase[bin] + o] = make_uint2(meta, __float_as_uint(v));
        }
    }
}

// ---------------- per-bin counting sort: bin-grouped rec -> row-sorted rec2 ----
__global__ __launch_bounds__(256) void k_sortbin(const int* __restrict__ binptr,
                                                 const uint2* __restrict__ rec,
                                                 uint2* __restrict__ rec2,
                                                 int* __restrict__ rowptr,
                                                 int n_rows, int nnz) {
    __shared__ int cnt[RPB];
    __shared__ int pos[RPB];
    int b = blockIdx.x, t = threadIdx.x;
    int s = binptr[b], e = binptr[b + 1];
    if (t < RPB) cnt[t] = 0;
    __syncthreads();
    for (int j = s + t; j < e; j += 256)
        atomicAdd(&cnt[rec[j].x >> 24], 1);
    __syncthreads();
    if (t < RPB) pos[t] = cnt[t];
    __syncthreads();
    for (int d = 1; d < RPB; d <<= 1) {
        int v = (t < RPB && t >= d) ? pos[t - d] : 0;
        __syncthreads();
        if (t < RPB && t >= d) pos[t] += v;
        __syncthreads();
    }
    int ex = (t < RPB) ? (pos[t] - cnt[t]) : 0;
    __syncthreads();
    if (t < RPB) {
        pos[t] = ex;
        int row = b * RPB + t;
        if (row < n_rows) rowptr[row] = s + ex;
    }
    if (b == 0 && t == 0) rowptr[n_rows] = nnz;
    __syncthreads();
    for (int j = s + t; j < e; j += 256) {
        uint2 r = rec[j];
        int o = atomicAdd(&pos[r.x >> 24], 1);
        rec2[s + o] = r;
    }
}

// ================= CSR SpMM, bf16 x: one row per 8-lane octet =================
// x row = 64 bf16 = 128 B; lane p in [0,8) loads 16 B (8 bf16), accumulates fp32.
__global__ __launch_bounds__(256) void k_spmm_bf(const int* __restrict__ rowptr,
                                                 const uint2* __restrict__ rec,
                                                 const bf16* __restrict__ x,
                                                 float* __restrict__ out,
                                                 int n_rows) {
    int row = blockIdx.x * 32 + (threadIdx.x >> 3);
    int p = threadIdx.x & 7;
    if (row >= n_rows) return;
    int s = rowptr[row], e = rowptr[row + 1];
    const uint4* xb = (const uint4*)x;   // 8 bf16 per uint4
    float a[8];
#pragma unroll
    for (int i = 0; i < 8; i++) a[i] = 0.0f;
    for (int j = s; j < e; j++) {
        uint2 r = rec[j];
        int col = r.x & 0xFFFFFF;
        float v = __uint_as_float(r.y);
        uint4 q = xb[(long)col * 8 + p];
        a[0] += v * __uint_as_float(q.x << 16);
        a[1] += v * __uint_as_float(q.x & 0xFFFF0000u);
        a[2] += v * __uint_as_float(q.y << 16);
        a[3] += v * __uint_as_float(q.y & 0xFFFF0000u);
        a[4] += v * __uint_as_float(q.z << 16);
        a[5] += v * __uint_as_float(q.z & 0xFFFF0000u);
        a[6] += v * __uint_as_float(q.w << 16);
        a[7] += v * __uint_as_float(q.w & 0xFFFF0000u);
    }
    float* o = out + (long)row * 64 + p * 8;
    *(float4*)(o + 0) = make_float4(a[0], a[1], a[2], a[3]);
    *(float4*)(o + 4) = make_float4(a[4], a[5], a[6], a[7]);
}

// ---------------- Y[M,64] = act(X[M,64] @ W[64,64] + b) -> bf16 ----------------
// ACT: 1 = elu, 2 = relu
template <int ACT>
__global__ __launch_bounds__(256) void k_gemm64(const float* __restrict__ X,
                                                const void* __restrict__ W,
                                                const void* __restrict__ b,
                                                bf16* __restrict__ Y, int M,
                                                const int* __restrict__ flag) {
    __shared__ float Wl[64][64];
    __shared__ float bl[64];
    int f = *flag;
    int tid = threadIdx.x;
    for (int i = tid; i < 4096; i += 256) Wl[i >> 6][i & 63] = ldf(W, i, f);
    if (tid < 64) bl[tid] = ldf(b, tid, f);
    __syncthreads();

    int r = blockIdx.x * 256 + tid;
    if (r >= M) return;
    const float* xr = X + (long)r * 64;

    float acc[64];
#pragma unroll
    for (int j = 0; j < 64; j++) acc[j] = bl[j];

    for (int k4 = 0; k4 < 64; k4 += 4) {
        float4 xv = *(const float4*)(xr + k4);
#pragma unroll
        for (int kk = 0; kk < 4; kk++) {
            float xs = (kk == 0) ? xv.x : (kk == 1) ? xv.y : (kk == 2) ? xv.z : xv.w;
#pragma unroll
            for (int j = 0; j < 64; j += 4) {
                float4 w4 = *(const float4*)&Wl[k4 + kk][j];
                acc[j + 0] += xs * w4.x;
                acc[j + 1] += xs * w4.y;
                acc[j + 2] += xs * w4.z;
                acc[j + 3] += xs * w4.w;
            }
        }
    }

    bf16* y = Y + (long)r * 64;
#pragma unroll
    for (int j = 0; j < 64; j++) {
        float v = acc[j];
        if (ACT == 2) v = fmaxf(v, 0.0f);
        else          v = (v > 0.0f) ? v : (expf(v) - 1.0f);
        y[j] = __float2bfloat16(v);
    }
}

// ---------------- fused NGCF layer + l2norm; ego fp32 in place + bf16 copy ----
__global__ __launch_bounds__(256) void k_layer(const float* __restrict__ S,
                                               float* __restrict__ E,
                                               bf16* __restrict__ E16,
                                               const void* __restrict__ Wgc,
                                               const void* __restrict__ bgc,
                                               const void* __restrict__ Wbi,
                                               const void* __restrict__ bbi,
                                               long woff, long boff,
                                               bf16* __restrict__ nm, int M,
                                               const int* __restrict__ flag) {
    __shared__ float W1[64][64];
    __shared__ float W2[64][64];
    __shared__ float bl[64];
    int f = *flag;
    int tid = threadIdx.x;
    for (int i = tid; i < 4096; i += 256) {
        W1[i >> 6][i & 63] = ldf(Wgc, woff + i, f);
        W2[i >> 6][i & 63] = ldf(Wbi, woff + i, f);
    }
    if (tid < 64) bl[tid] = ldf(bgc, boff + tid, f) + ldf(bbi, boff + tid, f);
    __syncthreads();

    int r = blockIdx.x * 256 + tid;
    if (r >= M) return;
    const float* sr = S + (long)r * 64;
    float* er = E + (long)r * 64;

    float acc[64];
#pragma unroll
    for (int j = 0; j < 64; j++) acc[j] = bl[j];

    for (int k4 = 0; k4 < 64; k4 += 4) {
        float4 sv = *(const float4*)(sr + k4);
        float4 ev = *(const float4*)(er + k4);
#pragma unroll
        for (int kk = 0; kk < 4; kk++) {
            float xs = (kk == 0) ? sv.x : (kk == 1) ? sv.y : (kk == 2) ? sv.z : sv.w;
            float xe = ((kk == 0) ? ev.x : (kk == 1) ? ev.y : (kk == 2) ? ev.z : ev.w) * xs;
#pragma unroll
            for (int j = 0; j < 64; j += 4) {
                float4 w1 = *(const float4*)&W1[k4 + kk][j];
                float4 w2 = *(const float4*)&W2[k4 + kk][j];
                acc[j + 0] += xs * w1.x + xe * w2.x;
                acc[j + 1] += xs * w1.y + xe * w2.y;
                acc[j + 2] += xs * w1.z + xe * w2.z;
                acc[j + 3] += xs * w1.w + xe * w2.w;
            }
        }
    }

    float ss = 0.0f;
#pragma unroll
    for (int j = 0; j < 64; j++) {
        float v = acc[j];
        v = (v > 0.0f) ? v : 0.2f * v;
        acc[j] = v;
        ss += v * v;
    }
    float sc = 1.0f / fmaxf(sqrtf(ss), 1e-12f);

    bf16* nr = nm + (long)r * 64;
    bf16* e16 = E16 + (long)r * 64;
#pragma unroll
    for (int j = 0; j < 64; j++) {
        er[j] = acc[j];
        e16[j] = __float2bfloat16(acc[j]);
        nr[j] = __float2bfloat16(acc[j] * sc);
    }
}

// ---------------- final gather into output ----------------
__global__ __launch_bounds__(64) void k_gather(const int* __restrict__ users,
                                               const int* __restrict__ pos,
                                               const int* __restrict__ neg,
                                               const void* __restrict__ ue,
                                               const void* __restrict__ ie,
                                               const bf16* __restrict__ n1,
                                               const bf16* __restrict__ n2,
                                               const bf16* __restrict__ n3,
                                               const bf16* __restrict__ uh,
                                               const bf16* __restrict__ ih,
                                               void* __restrict__ out,
                                               const int* __restrict__ flag) {
    int f = *flag;
    int b = blockIdx.x;           // 0..12287: [users | pos | neg] x 4096
    int which = b >> 12;
    int s = b & 4095;
    int lane = threadIdx.x;       // 64
    long ebase, nbase;
    const void* e0;
    const bf16* hh;
    if (which == 0) {
        int r = users[s];
        e0 = ue; ebase = (long)r * 64;
        hh = uh + (long)r * 64;
        nbase = (long)r * 64;
    } else {
        int r = (which == 1) ? pos[s] : neg[s];
        e0 = ie; ebase = (long)r * 64;
        hh = ih + (long)r * 64;
        nbase = (long)(N_USER + r) * 64;
    }
    float o0 = ldf(e0, ebase + lane, f);
    float o1 = __bfloat162float(n1[nbase + lane]);
    float o2 = __bfloat162float(n2[nbase + lane]);
    float o3 = __bfloat162float(n3[nbase + lane]);
    float o4 = __bfloat162float(hh[lane]);
    long ob = (long)b * 320;
    if (f) {
        float* o = (float*)out + ob;
        o[lane] = o0; o[64 + lane] = o1; o[128 + lane] = o2;
        o[192 + lane] = o3; o[256 + lane] = o4;
    } else {
        bf16* o = (bf16*)out + ob;
        o[lane]       = __float2bfloat16(o0);
        o[64 + lane]  = __float2bfloat16(o1);
        o[128 + lane] = __float2bfloat16(o2);
        o[192 + lane] = __float2bfloat16(o3);
        o[256 + lane] = __float2bfloat16(o4);
    }
}

// host-side helper: build row-sorted packed CSR for one graph
static void build_graph(const int* rows, const int* cols, const void* vals,
                        int nnz, int nb, int n_rows,
                        int* bincnt, int* binpos, int* binptr,
                        uint2* recTmp, uint2* rec2, int* rowptr,
                        const int* FLAG, hipStream_t stream) {
    int nchunks = (nnz + CHUNK - 1) / CHUNK;
    hipMemsetAsync(bincnt, 0, (size_t)nb * 4, stream);
    k_count_bin<<<nchunks, 256, 0, stream>>>(rows, bincnt, nnz, nb);
    k_scanbins<<<1, 1024, 0, stream>>>(bincnt, binptr, binpos, nb, nnz);
    k_scatter_bin<<<nchunks, 256, 0, stream>>>(rows, cols, vals, recTmp, binpos, nnz, nb, FLAG);
    k_sortbin<<<nb, 256, 0, stream>>>(binptr, recTmp, rec2, rowptr, n_rows, nnz);
}

extern "C" void kernel_launch(void* const* d_in, const int* in_sizes, int n_in,
                              void* d_out, int out_size, void* d_ws, size_t ws_size,
                              hipStream_t stream) {
    const int* users = (const int*)d_in[0];
    const int* pos   = (const int*)d_in[1];
    const int* neg   = (const int*)d_in[2];
    const int* adj_r = (const int*)d_in[3];
    const int* adj_c = (const int*)d_in[4];
    const void* adj_v = d_in[5];
    const int* ug_r  = (const int*)d_in[6];
    const int* ug_c  = (const int*)d_in[7];
    const void* ug_v = d_in[8];
    const int* ig_r  = (const int*)d_in[9];
    const int* ig_c  = (const int*)d_in[10];
    const void* ig_v = d_in[11];
    const void* ue   = d_in[12];
    const void* ie   = d_in[13];
    const void* Wgc  = d_in[14];
    const void* bgc  = d_in[15];
    const void* Wbi  = d_in[16];
    const void* bbi  = d_in[17];
    const void* Wu0  = d_in[18];
    const void* bu0  = d_in[19];
    const void* Wu1  = d_in[20];
    const void* bu1  = d_in[21];
    const void* Wi0  = d_in[22];
    const void* bi0  = d_in[23];
    const void* Wi1  = d_in[24];
    const void* bi1  = d_in[25];

    char* ws = (char*)d_ws;
    int*   FLAG  = (int*)(ws + 0);                       // 256 B
    float* egoA  = (float*)(ws + 256);                   // 46,080,000
    float* T1    = (float*)(ws + 46080256L);             // 46,080,000
    bf16*  ego16 = (bf16*)(ws + 92160256L);              // 23,040,000
    bf16*  UH    = (bf16*)(ws + 115200256L);             //  7,680,000
    bf16*  IH    = (bf16*)(ws + 122880256L);             // 15,360,000
    bf16*  NM1   = (bf16*)(ws + 138240256L);             // 23,040,000
    bf16*  NM2   = (bf16*)(ws + 161280256L);             // 23,040,000
    bf16*  NM3   = (bf16*)(ws + 184320256L);             // 23,040,000
    // T2 (bf16, <=15.36 MB) aliases NM2 region: dead before layer k=1 writes NM2
    bf16*  T2    = (bf16*)(ws + 161280256L);
    // recTmp aliases T1: all builds finish before any SpMM writes T1
    uint2* recTmp = (uint2*)(ws + 46080256L);
    uint2* rec2A = (uint2*)(ws + 207360256L);            // 28,800,000
    uint2* rec2U = (uint2*)(ws + 236160256L);            //  7,680,000
    uint2* rec2I = (uint2*)(ws + 243840256L);            // 15,360,000
    int* rowptrA = (int*)(ws + 259200256L);              //    720,128
    int* rowptrU = (int*)(ws + 259920384L);              //    240,128
    int* rowptrI = (int*)(ws + 260160512L);              //    480,128
    int* binptr  = (int*)(ws + 260640640L);              //      6,400
    int* bincnt  = (int*)(ws + 260647040L);              //      6,144
    int* binpos  = (int*)(ws + 260653184L);              //      6,144
                                                         // end 260,659,328 (< 261,120,256 proven)

    k_detect<<<1, 64, 0, stream>>>(adj_v, FLAG);
    k_cast<<<45000, 256, 0, stream>>>(ue, ie, egoA, ego16, FLAG);

    // ---- build row-sorted packed CSR for the three graphs (recTmp aliases T1) ----
    build_graph(ug_r,  ug_c,  ug_v,  NNZ_UG,  NB_UG,  N_USER,
                bincnt, binpos, binptr, recTmp, rec2U, rowptrU, FLAG, stream);
    build_graph(ig_r,  ig_c,  ig_v,  NNZ_IG,  NB_IG,  N_ITEM,
                bincnt, binpos, binptr, recTmp, rec2I, rowptrI, FLAG, stream);
    build_graph(adj_r, adj_c, adj_v, NNZ_ADJ, NB_ADJ, NTOT,
                bincnt, binpos, binptr, recTmp, rec2A, rowptrA, FLAG, stream);

    // ---- user MLP branch ----
    k_spmm_bf<<<(N_USER + 31) / 32, 256, 0, stream>>>(rowptrU, rec2U, ego16, T1, N_USER);
    k_gemm64<1><<<(N_USER + 255) / 256, 256, 0, stream>>>(T1, Wu0, bu0, T2, N_USER, FLAG);
    k_spmm_bf<<<(N_USER + 31) / 32, 256, 0, stream>>>(rowptrU, rec2U, T2, T1, N_USER);
    k_gemm64<2><<<(N_USER + 255) / 256, 256, 0, stream>>>(T1, Wu1, bu1, UH, N_USER, FLAG);

    // ---- item MLP branch ----
    const bf16* ego16I = ego16 + (size_t)N_USER * 64;
    k_spmm_bf<<<(N_ITEM + 31) / 32, 256, 0, stream>>>(rowptrI, rec2I, ego16I, T1, N_ITEM);
    k_gemm64<1><<<(N_ITEM + 255) / 256, 256, 0, stream>>>(T1, Wi0, bi0, T2, N_ITEM, FLAG);
    k_spmm_bf<<<(N_ITEM + 31) / 32, 256, 0, stream>>>(rowptrI, rec2I, T2, T1, N_ITEM);
    k_gemm64<2><<<(N_ITEM + 255) / 256, 256, 0, stream>>>(T1, Wi1, bi1, IH, N_ITEM, FLAG);

    // ---- 3 NGCF layers (ego fp32 in place, bf16 copy for next gather) ----
    bf16* norms[3] = {NM1, NM2, NM3};
    for (int k = 0; k < 3; k++) {
        k_spmm_bf<<<(NTOT + 31) / 32, 256, 0, stream>>>(rowptrA, rec2A, ego16, T1, NTOT);
        k_layer<<<(NTOT + 255) / 256, 256, 0, stream>>>(T1, egoA, ego16, Wgc, bgc, Wbi, bbi,
                                                        (long)k * 4096, (long)k * 64,
                                                        norms[k], NTOT, FLAG);
    }

    // ---- output gather ----
    k_gather<<<12288, 64, 0, stream>>>(users, pos, neg, ue, ie, NM1, NM2, NM3, UH, IH,
                                       d_out, FLAG);
}

// Round 7
// 1559.045 us; speedup vs baseline: 4.4556x; 1.0184x over previous
//
#include <hip/hip_runtime.h>
#include <hip/hip_bf16.h>

#define N_USER 60000
#define N_ITEM 120000
#define NTOT   180000
#define NNZ_ADJ 3600000
#define NNZ_UG   960000
#define NNZ_IG  1920000

#define RPB    128          // rows per bin
#define NB_ADJ ((NTOT  + RPB - 1) / RPB)   // 1407
#define NB_UG  ((N_USER+ RPB - 1) / RPB)   // 469
#define NB_IG  ((N_ITEM+ RPB - 1) / RPB)   // 938
#define CAPA   3072         // bin capacity: mean 2560 + 10 sigma
#define CAPU   2560         // mean 2047 + 11 sigma
#define CAPI   2560

typedef __hip_bfloat16 bf16;

// load float element i from input tensor of unknown dtype: flag=1 -> fp32, 0 -> bf16
__device__ __forceinline__ float ldf(const void* p, long i, int f) {
    return f ? ((const float*)p)[i] : __bfloat162float(((const bf16*)p)[i]);
}

// ---------------- dtype detector (adj_vals >= 0 -> bf16 words have bit15==0) ----
__global__ void k_detect(const void* __restrict__ vals, int* __restrict__ flag) {
    if (threadIdx.x == 0 && blockIdx.x == 0) {
        const unsigned short* w = (const unsigned short*)vals;
        int cnt = 0;
        for (int i = 0; i < 512; i += 2) cnt += (w[i] >> 15) & 1;
        *flag = (cnt > 16) ? 1 : 0;
    }
}

// ---------------- cast user/item emb -> ego bf16 ----------------
__global__ __launch_bounds__(256) void k_cast16(const void* __restrict__ ue,
                                                const void* __restrict__ ie,
                                                bf16* __restrict__ ego16,
                                                const int* __restrict__ flag) {
    int f = *flag;
    long i = (long)blockIdx.x * 256 + threadIdx.x;   // NTOT*64 = 11,520,000
    const long uN = (long)N_USER * 64;
    if (i < (long)NTOT * 64) {
        float v = (i < uN) ? ldf(ue, i, f) : ldf(ie, i - uN, f);
        ego16[i] = __float2bfloat16(v);
    }
}

// ================= one-pass binned build =================
// binpos: one fill cursor per bin, padded to its own 64B cache line (stride 16 ints)
__global__ __launch_bounds__(256) void k_initpos(int* __restrict__ binpos, int nb, int cap) {
    int i = blockIdx.x * 256 + threadIdx.x;
    if (i < nb) binpos[i * 16] = i * cap;
}

// one thread per edge; slot via padded-line global atomic; packs {rl|col, val_f32}
__global__ __launch_bounds__(256) void k_scatter2(const int* __restrict__ rows,
                                                  const int* __restrict__ cols,
                                                  const void* __restrict__ vals,
                                                  uint2* __restrict__ rec,
                                                  int* __restrict__ binpos,
                                                  int nnz,
                                                  const int* __restrict__ flag) {
    int f = *flag;
    int e = blockIdx.x * 256 + threadIdx.x;
    if (e >= nnz) return;
    int r = rows[e];
    int bin = r >> 7;
    int slot = atomicAdd(&binpos[bin * 16], 1);
    unsigned meta = ((unsigned)(r & 127) << 24) | (unsigned)cols[e];
    rec[slot] = make_uint2(meta, __float_as_uint(ldf(vals, e, f)));
}

// ---------------- per-bin counting sort: bin-grouped rec -> row-sorted rec2 ----
// Fixed-capacity bin regions; emits per-row [rstart, rend).
__global__ __launch_bounds__(256) void k_sortbin(const uint2* __restrict__ rec,
                                                 uint2* __restrict__ rec2,
                                                 int* __restrict__ rstart,
                                                 int* __restrict__ rend,
                                                 const int* __restrict__ binpos,
                                                 int cap, int n_rows) {
    __shared__ int cnt[RPB];
    __shared__ int pos[RPB];
    int b = blockIdx.x, t = threadIdx.x;
    int s = b * cap;
    int e = binpos[b * 16];          // final fill cursor
    if (t < RPB) cnt[t] = 0;
    __syncthreads();
    for (int j = s + t; j < e; j += 256)
        atomicAdd(&cnt[rec[j].x >> 24], 1);
    __syncthreads();
    if (t < RPB) pos[t] = cnt[t];
    __syncthreads();
    for (int d = 1; d < RPB; d <<= 1) {
        int v = (t < RPB && t >= d) ? pos[t - d] : 0;
        __syncthreads();
        if (t < RPB && t >= d) pos[t] += v;
        __syncthreads();
    }
    int ex = (t < RPB) ? (pos[t] - cnt[t]) : 0;   // exclusive prefix
    __syncthreads();
    if (t < RPB) {
        pos[t] = ex;
        int row = b * RPB + t;
        if (row < n_rows) {
            rstart[row] = s + ex;
            rend[row]   = s + ex + cnt[t];
        }
    }
    __syncthreads();
    for (int j = s + t; j < e; j += 256) {
        uint2 r = rec[j];
        int o = atomicAdd(&pos[r.x >> 24], 1);
        rec2[s + o] = r;
    }
}

// ================= CSR SpMM, bf16 x: one row per 8-lane octet =================
__global__ __launch_bounds__(256) void k_spmm_bf(const int* __restrict__ rstart,
                                                 const int* __restrict__ rend,
                                                 const uint2* __restrict__ rec,
                                                 const bf16* __restrict__ x,
                                                 float* __restrict__ out,
                                                 int n_rows) {
    int row = blockIdx.x * 32 + (threadIdx.x >> 3);
    int p = threadIdx.x & 7;
    if (row >= n_rows) return;
    int s = rstart[row], e = rend[row];
    const uint4* xb = (const uint4*)x;   // 8 bf16 per uint4
    float a[8];
#pragma unroll
    for (int i = 0; i < 8; i++) a[i] = 0.0f;
    for (int j = s; j < e; j++) {
        uint2 r = rec[j];
        int col = r.x & 0xFFFFFF;
        float v = __uint_as_float(r.y);
        uint4 q = xb[(long)col * 8 + p];
        a[0] += v * __uint_as_float(q.x << 16);
        a[1] += v * __uint_as_float(q.x & 0xFFFF0000u);
        a[2] += v * __uint_as_float(q.y << 16);
        a[3] += v * __uint_as_float(q.y & 0xFFFF0000u);
        a[4] += v * __uint_as_float(q.z << 16);
        a[5] += v * __uint_as_float(q.z & 0xFFFF0000u);
        a[6] += v * __uint_as_float(q.w << 16);
        a[7] += v * __uint_as_float(q.w & 0xFFFF0000u);
    }
    float* o = out + (long)row * 64 + p * 8;
    *(float4*)(o + 0) = make_float4(a[0], a[1], a[2], a[3]);
    *(float4*)(o + 4) = make_float4(a[4], a[5], a[6], a[7]);
}

// ---------------- Y[M,64] = act(X[M,64] @ W[64,64] + b) -> bf16 ----------------
// ACT: 1 = elu, 2 = relu
template <int ACT>
__global__ __launch_bounds__(256) void k_gemm64(const float* __restrict__ X,
                                                const void* __restrict__ W,
                                                const void* __restrict__ b,
                                                bf16* __restrict__ Y, int M,
                                                const int* __restrict__ flag) {
    __shared__ float Wl[64][64];
    __shared__ float bl[64];
    int f = *flag;
    int tid = threadIdx.x;
    for (int i = tid; i < 4096; i += 256) Wl[i >> 6][i & 63] = ldf(W, i, f);
    if (tid < 64) bl[tid] = ldf(b, tid, f);
    __syncthreads();

    int r = blockIdx.x * 256 + tid;
    if (r >= M) return;
    const float* xr = X + (long)r * 64;

    float acc[64];
#pragma unroll
    for (int j = 0; j < 64; j++) acc[j] = bl[j];

    for (int k4 = 0; k4 < 64; k4 += 4) {
        float4 xv = *(const float4*)(xr + k4);
#pragma unroll
        for (int kk = 0; kk < 4; kk++) {
            float xs = (kk == 0) ? xv.x : (kk == 1) ? xv.y : (kk == 2) ? xv.z : xv.w;
#pragma unroll
            for (int j = 0; j < 64; j += 4) {
                float4 w4 = *(const float4*)&Wl[k4 + kk][j];
                acc[j + 0] += xs * w4.x;
                acc[j + 1] += xs * w4.y;
                acc[j + 2] += xs * w4.z;
                acc[j + 3] += xs * w4.w;
            }
        }
    }

    bf16* y = Y + (long)r * 64;
#pragma unroll
    for (int j = 0; j < 64; j++) {
        float v = acc[j];
        if (ACT == 2) v = fmaxf(v, 0.0f);
        else          v = (v > 0.0f) ? v : (expf(v) - 1.0f);
        y[j] = __float2bfloat16(v);
    }
}

// ---------------- fused NGCF layer + l2norm; ego bf16 updated IN PLACE --------
// ego = leaky_relu(S@Wgc + bgc + (ego*S)@Wbi + bbi, 0.2); nm = l2norm(ego) bf16
__global__ __launch_bounds__(256) void k_layer(const float* __restrict__ S,
                                               bf16* __restrict__ E16,
                                               const void* __restrict__ Wgc,
                                               const void* __restrict__ bgc,
                                               const void* __restrict__ Wbi,
                                               const void* __restrict__ bbi,
                                               long woff, long boff,
                                               bf16* __restrict__ nm, int M,
                                               const int* __restrict__ flag) {
    __shared__ float W1[64][64];
    __shared__ float W2[64][64];
    __shared__ float bl[64];
    int f = *flag;
    int tid = threadIdx.x;
    for (int i = tid; i < 4096; i += 256) {
        W1[i >> 6][i & 63] = ldf(Wgc, woff + i, f);
        W2[i >> 6][i & 63] = ldf(Wbi, woff + i, f);
    }
    if (tid < 64) bl[tid] = ldf(bgc, boff + tid, f) + ldf(bbi, boff + tid, f);
    __syncthreads();

    int r = blockIdx.x * 256 + tid;
    if (r >= M) return;
    const float* sr = S + (long)r * 64;
    const uint2* ep = (const uint2*)(E16 + (long)r * 64);   // 4 bf16 per uint2

    float acc[64];
#pragma unroll
    for (int j = 0; j < 64; j++) acc[j] = bl[j];

    for (int k4 = 0; k4 < 64; k4 += 4) {
        float4 sv = *(const float4*)(sr + k4);
        uint2 eq = ep[k4 >> 2];
        float e0 = __uint_as_float(eq.x << 16);
        float e1 = __uint_as_float(eq.x & 0xFFFF0000u);
        float e2 = __uint_as_float(eq.y << 16);
        float e3 = __uint_as_float(eq.y & 0xFFFF0000u);
#pragma unroll
        for (int kk = 0; kk < 4; kk++) {
            float xs = (kk == 0) ? sv.x : (kk == 1) ? sv.y : (kk == 2) ? sv.z : sv.w;
            float xe = ((kk == 0) ? e0 : (kk == 1) ? e1 : (kk == 2) ? e2 : e3) * xs;
#pragma unroll
            for (int j = 0; j < 64; j += 4) {
                float4 w1 = *(const float4*)&W1[k4 + kk][j];
                float4 w2 = *(const float4*)&W2[k4 + kk][j];
                acc[j + 0] += xs * w1.x + xe * w2.x;
                acc[j + 1] += xs * w1.y + xe * w2.y;
                acc[j + 2] += xs * w1.z + xe * w2.z;
                acc[j + 3] += xs * w1.w + xe * w2.w;
            }
        }
    }

    float ss = 0.0f;
#pragma unroll
    for (int j = 0; j < 64; j++) {
        float v = acc[j];
        v = (v > 0.0f) ? v : 0.2f * v;
        acc[j] = v;
        ss += v * v;
    }
    float sc = 1.0f / fmaxf(sqrtf(ss), 1e-12f);

    bf16* nr = nm + (long)r * 64;
    bf16* er = E16 + (long)r * 64;
#pragma unroll
    for (int j = 0; j < 64; j++) {
        er[j] = __float2bfloat16(acc[j]);
        nr[j] = __float2bfloat16(acc[j] * sc);
    }
}

// ---------------- final gather into output ----------------
__global__ __launch_bounds__(64) void k_gather(const int* __restrict__ users,
                                               const int* __restrict__ pos,
                                               const int* __restrict__ neg,
                                               const void* __restrict__ ue,
                                               const void* __restrict__ ie,
                                               const bf16* __restrict__ n1,
                                               const bf16* __restrict__ n2,
                                               const bf16* __restrict__ n3,
                                               const bf16* __restrict__ uh,
                                               const bf16* __restrict__ ih,
                                               void* __restrict__ out,
                                               const int* __restrict__ flag) {
    int f = *flag;
    int b = blockIdx.x;           // 0..12287: [users | pos | neg] x 4096
    int which = b >> 12;
    int s = b & 4095;
    int lane = threadIdx.x;       // 64
    long ebase, nbase;
    const void* e0;
    const bf16* hh;
    if (which == 0) {
        int r = users[s];
        e0 = ue; ebase = (long)r * 64;
        hh = uh + (long)r * 64;
        nbase = (long)r * 64;
    } else {
        int r = (which == 1) ? pos[s] : neg[s];
        e0 = ie; ebase = (long)r * 64;
        hh = ih + (long)r * 64;
        nbase = (long)(N_USER + r) * 64;
    }
    float o0 = ldf(e0, ebase + lane, f);
    float o1 = __bfloat162float(n1[nbase + lane]);
    float o2 = __bfloat162float(n2[nbase + lane]);
    float o3 = __bfloat162float(n3[nbase + lane]);
    float o4 = __bfloat162float(hh[lane]);
    long ob = (long)b * 320;
    if (f) {
        float* o = (float*)out + ob;
        o[lane] = o0; o[64 + lane] = o1; o[128 + lane] = o2;
        o[192 + lane] = o3; o[256 + lane] = o4;
    } else {
        bf16* o = (bf16*)out + ob;
        o[lane]       = __float2bfloat16(o0);
        o[64 + lane]  = __float2bfloat16(o1);
        o[128 + lane] = __float2bfloat16(o2);
        o[192 + lane] = __float2bfloat16(o3);
        o[256 + lane] = __float2bfloat16(o4);
    }
}

// host-side helper: build row-sorted packed bins for one graph
static void build_graph(const int* rows, const int* cols, const void* vals,
                        int nnz, int nb, int cap, int n_rows,
                        int* binpos, uint2* recTmp, uint2* rec2,
                        int* rstart, int* rend,
                        const int* FLAG, hipStream_t stream) {
    k_initpos<<<(nb + 255) / 256, 256, 0, stream>>>(binpos, nb, cap);
    k_scatter2<<<(nnz + 255) / 256, 256, 0, stream>>>(rows, cols, vals, recTmp, binpos, nnz, FLAG);
    k_sortbin<<<nb, 256, 0, stream>>>(recTmp, rec2, rstart, rend, binpos, cap, n_rows);
}

extern "C" void kernel_launch(void* const* d_in, const int* in_sizes, int n_in,
                              void* d_out, int out_size, void* d_ws, size_t ws_size,
                              hipStream_t stream) {
    const int* users = (const int*)d_in[0];
    const int* pos   = (const int*)d_in[1];
    const int* neg   = (const int*)d_in[2];
    const int* adj_r = (const int*)d_in[3];
    const int* adj_c = (const int*)d_in[4];
    const void* adj_v = d_in[5];
    const int* ug_r  = (const int*)d_in[6];
    const int* ug_c  = (const int*)d_in[7];
    const void* ug_v = d_in[8];
    const int* ig_r  = (const int*)d_in[9];
    const int* ig_c  = (const int*)d_in[10];
    const void* ig_v = d_in[11];
    const void* ue   = d_in[12];
    const void* ie   = d_in[13];
    const void* Wgc  = d_in[14];
    const void* bgc  = d_in[15];
    const void* Wbi  = d_in[16];
    const void* bbi  = d_in[17];
    const void* Wu0  = d_in[18];
    const void* bu0  = d_in[19];
    const void* Wu1  = d_in[20];
    const void* bu1  = d_in[21];
    const void* Wi0  = d_in[22];
    const void* bi0  = d_in[23];
    const void* Wi1  = d_in[24];
    const void* bi1  = d_in[25];

    char* ws = (char*)d_ws;
    int*   FLAG  = (int*)(ws + 0);                       // 256 B
    float* T1    = (float*)(ws + 256);                   // 46,080,000 (fp32 NTOT*64)
    bf16*  ego16 = (bf16*)(ws + 46080256L);              // 23,040,000
    bf16*  UH    = (bf16*)(ws + 69120256L);              //  7,680,000
    bf16*  IH    = (bf16*)(ws + 76800256L);              // 15,360,000
    bf16*  NM1   = (bf16*)(ws + 92160256L);              // 23,040,000
    bf16*  NM2   = (bf16*)(ws + 115200256L);             // 23,040,000
    bf16*  NM3   = (bf16*)(ws + 138240256L);             // 23,040,000
    // T2 (bf16, <=15.36 MB) aliases NM2 region: dead before layer k=1 writes NM2
    bf16*  T2    = (bf16*)(ws + 115200256L);
    // recTmp aliases T1: builds finish before any SpMM writes T1 (adj needs 34.6 MB < 46 MB)
    uint2* recTmp = (uint2*)(ws + 256);
    uint2* rec2A = (uint2*)(ws + 161280256L);            // 1407*3072*8 = 34,578,432
    uint2* rec2U = (uint2*)(ws + 195858688L);            //  469*2560*8 =  9,605,120
    uint2* rec2I = (uint2*)(ws + 205463808L);            //  938*2560*8 = 19,210,240
    int* rstartA = (int*)(ws + 224674048L);              //    720,000
    int* rendA   = (int*)(ws + 225394048L);              //    720,000
    int* rstartU = (int*)(ws + 226114048L);              //    240,000
    int* rendU   = (int*)(ws + 226354048L);              //    240,000
    int* rstartI = (int*)(ws + 226594048L);              //    480,000
    int* rendI   = (int*)(ws + 227074048L);              //    480,000
    int* binpos  = (int*)(ws + 227554048L);              //     90,048 (64B-aligned, 1 line/bin)
                                                         // end 227,644,096 (< 261,120,256 proven)

    k_detect<<<1, 64, 0, stream>>>(adj_v, FLAG);
    k_cast16<<<45000, 256, 0, stream>>>(ue, ie, ego16, FLAG);

    // ---- build row-sorted packed bins for the three graphs (recTmp aliases T1) ----
    build_graph(ug_r,  ug_c,  ug_v,  NNZ_UG,  NB_UG,  CAPU, N_USER,
                binpos, recTmp, rec2U, rstartU, rendU, FLAG, stream);
    build_graph(ig_r,  ig_c,  ig_v,  NNZ_IG,  NB_IG,  CAPI, N_ITEM,
                binpos, recTmp, rec2I, rstartI, rendI, FLAG, stream);
    build_graph(adj_r, adj_c, adj_v, NNZ_ADJ, NB_ADJ, CAPA, NTOT,
                binpos, recTmp, rec2A, rstartA, rendA, FLAG, stream);

    // ---- user MLP branch ----
    k_spmm_bf<<<(N_USER + 31) / 32, 256, 0, stream>>>(rstartU, rendU, rec2U, ego16, T1, N_USER);
    k_gemm64<1><<<(N_USER + 255) / 256, 256, 0, stream>>>(T1, Wu0, bu0, T2, N_USER, FLAG);
    k_spmm_bf<<<(N_USER + 31) / 32, 256, 0, stream>>>(rstartU, rendU, rec2U, T2, T1, N_USER);
    k_gemm64<2><<<(N_USER + 255) / 256, 256, 0, stream>>>(T1, Wu1, bu1, UH, N_USER, FLAG);

    // ---- item MLP branch ----
    const bf16* ego16I = ego16 + (size_t)N_USER * 64;
    k_spmm_bf<<<(N_ITEM + 31) / 32, 256, 0, stream>>>(rstartI, rendI, rec2I, ego16I, T1, N_ITEM);
    k_gemm64<1><<<(N_ITEM + 255) / 256, 256, 0, stream>>>(T1, Wi0, bi0, T2, N_ITEM, FLAG);
    k_spmm_bf<<<(N_ITEM + 31) / 32, 256, 0, stream>>>(rstartI, rendI, rec2I, T2, T1, N_ITEM);
    k_gemm64<2><<<(N_ITEM + 255) / 256, 256, 0, stream>>>(T1, Wi1, bi1, IH, N_ITEM, FLAG);

    // ---- 3 NGCF layers (ego bf16 in place; norm fused) ----
    bf16* norms[3] = {NM1, NM2, NM3};
    for (int k = 0; k < 3; k++) {
        k_spmm_bf<<<(NTOT + 31) / 32, 256, 0, stream>>>(rstartA, rendA, rec2A, ego16, T1, NTOT);
        k_layer<<<(NTOT + 255) / 256, 256, 0, stream>>>(T1, ego16, Wgc, bgc, Wbi, bbi,
                                                        (long)k * 4096, (long)k * 64,
                                                        norms[k], NTOT, FLAG);
    }

    // ---- output gather ----
    k_gather<<<12288, 64, 0, stream>>>(users, pos, neg, ue, ie, NM1, NM2, NM3, UH, IH,
                                       d_out, FLAG);
}

// Round 8
// 1419.682 us; speedup vs baseline: 4.8930x; 1.0982x over previous
//
#include <hip/hip_runtime.h>
#include <hip/hip_bf16.h>

#define N_USER 60000
#define N_ITEM 120000
#define NTOT   180000
#define NNZ_ADJ 3600000
#define NNZ_UG   960000
#define NNZ_IG  1920000

#define RSB     2048        // rows per super-bin
#define NSB_ADJ ((NTOT  + RSB - 1) / RSB)   // 88
#define NSB_UG  ((N_USER+ RSB - 1) / RSB)   // 30
#define NSB_IG  ((N_ITEM+ RSB - 1) / RSB)   // 59
#define CAPA_SB 43008       // mean 40960 + 10 sigma
#define CAPU_SB 34816       // mean 32768 + 11 sigma
#define CAPI_SB 34816       // mean 32768 + 11 sigma
#define CHUNK   4096

typedef __hip_bfloat16 bf16;

// load float element i from input tensor of unknown dtype: flag=1 -> fp32, 0 -> bf16
__device__ __forceinline__ float ldf(const void* p, long i, int f) {
    return f ? ((const float*)p)[i] : __bfloat162float(((const bf16*)p)[i]);
}

// ---------------- dtype detector (adj_vals >= 0 -> bf16 words have bit15==0) ----
__global__ void k_detect(const void* __restrict__ vals, int* __restrict__ flag) {
    if (threadIdx.x == 0 && blockIdx.x == 0) {
        const unsigned short* w = (const unsigned short*)vals;
        int cnt = 0;
        for (int i = 0; i < 512; i += 2) cnt += (w[i] >> 15) & 1;
        *flag = (cnt > 16) ? 1 : 0;
    }
}

// ---------------- cast user/item emb -> ego bf16 ----------------
__global__ __launch_bounds__(256) void k_cast16(const void* __restrict__ ue,
                                                const void* __restrict__ ie,
                                                bf16* __restrict__ ego16,
                                                const int* __restrict__ flag) {
    int f = *flag;
    long i = (long)blockIdx.x * 256 + threadIdx.x;   // NTOT*64 = 11,520,000
    const long uN = (long)N_USER * 64;
    if (i < (long)NTOT * 64) {
        float v = (i < uN) ? ldf(ue, i, f) : ldf(ie, i - uN, f);
        ego16[i] = __float2bfloat16(v);
    }
}

// ================= two-level binned build =================
// sbpos: one fill cursor per super-bin, one 64B line each (stride 16 ints)
__global__ __launch_bounds__(256) void k_initpos(int* __restrict__ sbpos, int nsb, int cap) {
    int i = blockIdx.x * 256 + threadIdx.x;
    if (i < nsb) sbpos[i * 16] = i * cap;
}

// L1: partition edges into <=88 super-bins (2048 rows each).
// LDS count -> bulk reservation -> LDS-offset emit => contiguous ~370B runs per bin.
// Record: {rl(11b)<<18 | col(18b), val_f32}
__global__ __launch_bounds__(256) void k_part(const int* __restrict__ rows,
                                              const int* __restrict__ cols,
                                              const void* __restrict__ vals,
                                              uint2* __restrict__ rec,
                                              int* __restrict__ sbpos,
                                              int nnz,
                                              const int* __restrict__ flag) {
    __shared__ int lcnt[96];
    __shared__ int lbase[96];
    int f = *flag;
    int t = threadIdx.x;
    int base = blockIdx.x * CHUNK;
    if (t < 96) lcnt[t] = 0;
    __syncthreads();
    for (int k = 0; k < CHUNK / 256; k++) {
        int e = base + k * 256 + t;
        if (e < nnz) atomicAdd(&lcnt[rows[e] >> 11], 1);
    }
    __syncthreads();
    if (t < 96) {
        int c = lcnt[t];
        lbase[t] = c ? atomicAdd(&sbpos[t * 16], c) : 0;
        lcnt[t] = 0;
    }
    __syncthreads();
    for (int k = 0; k < CHUNK / 256; k++) {
        int e = base + k * 256 + t;
        if (e < nnz) {
            int r = rows[e];
            int sb = r >> 11;
            int o = atomicAdd(&lcnt[sb], 1);
            unsigned meta = ((unsigned)(r & 2047) << 18) | (unsigned)cols[e];
            rec[lbase[sb] + o] = make_uint2(meta, __float_as_uint(ldf(vals, e, f)));
        }
    }
}

// L2: per-super-bin counting sort into row order; emits absolute [rstart, rend).
// One 1024-thread block per super-bin; reads/writes stay in its ~340KB region (L2-local).
__global__ __launch_bounds__(1024) void k_sortsb(const uint2* __restrict__ rec,
                                                 uint2* __restrict__ rec2,
                                                 int* __restrict__ rstart,
                                                 int* __restrict__ rend,
                                                 const int* __restrict__ sbpos,
                                                 int cap, int n_rows) {
    __shared__ int cnt[RSB];
    __shared__ int pos[RSB];
    __shared__ int carry;
    int b = blockIdx.x, t = threadIdx.x;
    int s = b * cap;
    int e = sbpos[b * 16];           // final fill cursor
    cnt[t] = 0; cnt[t + 1024] = 0;
    if (t == 0) carry = 0;
    __syncthreads();
    for (int j = s + t; j < e; j += 1024)
        atomicAdd(&cnt[rec[j].x >> 18], 1);
    __syncthreads();
    // exclusive scan of 2048 counters, two 1024-tiles with carry
    for (int tile = 0; tile < 2; tile++) {
        int i = tile * 1024 + t;
        int v = cnt[i];
        pos[i] = v;
        __syncthreads();
        for (int d = 1; d < 1024; d <<= 1) {
            int w = (t >= d) ? pos[i - d] : 0;
            __syncthreads();
            if (t >= d) pos[i] += w;
            __syncthreads();
        }
        int inc = pos[i];            // inclusive within tile
        int ex  = carry + inc - v;   // exclusive global
        __syncthreads();
        pos[i] = ex;
        if (t == 1023) carry += inc;
        __syncthreads();
    }
    int row0 = b * RSB;
    for (int i = t; i < RSB; i += 1024) {
        int row = row0 + i;
        if (row < n_rows) {
            rstart[row] = s + pos[i];
            rend[row]   = s + pos[i] + cnt[i];
        }
    }
    __syncthreads();
    for (int j = s + t; j < e; j += 1024) {
        uint2 r = rec[j];
        int o = atomicAdd(&pos[r.x >> 18], 1);
        rec2[s + o] = r;
    }
}

// ================= CSR SpMM, bf16 x: one row per 8-lane octet =================
__global__ __launch_bounds__(256) void k_spmm_bf(const int* __restrict__ rstart,
                                                 const int* __restrict__ rend,
                                                 const uint2* __restrict__ rec,
                                                 const bf16* __restrict__ x,
                                                 float* __restrict__ out,
                                                 int n_rows) {
    int row = blockIdx.x * 32 + (threadIdx.x >> 3);
    int p = threadIdx.x & 7;
    if (row >= n_rows) return;
    int s = rstart[row], e = rend[row];
    const uint4* xb = (const uint4*)x;   // 8 bf16 per uint4
    float a[8];
#pragma unroll
    for (int i = 0; i < 8; i++) a[i] = 0.0f;
    for (int j = s; j < e; j++) {
        uint2 r = rec[j];
        int col = r.x & 0x3FFFF;
        float v = __uint_as_float(r.y);
        uint4 q = xb[(long)col * 8 + p];
        a[0] += v * __uint_as_float(q.x << 16);
        a[1] += v * __uint_as_float(q.x & 0xFFFF0000u);
        a[2] += v * __uint_as_float(q.y << 16);
        a[3] += v * __uint_as_float(q.y & 0xFFFF0000u);
        a[4] += v * __uint_as_float(q.z << 16);
        a[5] += v * __uint_as_float(q.z & 0xFFFF0000u);
        a[6] += v * __uint_as_float(q.w << 16);
        a[7] += v * __uint_as_float(q.w & 0xFFFF0000u);
    }
    float* o = out + (long)row * 64 + p * 8;
    *(float4*)(o + 0) = make_float4(a[0], a[1], a[2], a[3]);
    *(float4*)(o + 4) = make_float4(a[4], a[5], a[6], a[7]);
}

// ---------------- Y[M,64] = act(X[M,64] @ W[64,64] + b) -> bf16 ----------------
// ACT: 1 = elu, 2 = relu
template <int ACT>
__global__ __launch_bounds__(256) void k_gemm64(const float* __restrict__ X,
                                                const void* __restrict__ W,
                                                const void* __restrict__ b,
                                                bf16* __restrict__ Y, int M,
                                                const int* __restrict__ flag) {
    __shared__ float Wl[64][64];
    __shared__ float bl[64];
    int f = *flag;
    int tid = threadIdx.x;
    for (int i = tid; i < 4096; i += 256) Wl[i >> 6][i & 63] = ldf(W, i, f);
    if (tid < 64) bl[tid] = ldf(b, tid, f);
    __syncthreads();

    int r = blockIdx.x * 256 + tid;
    if (r >= M) return;
    const float* xr = X + (long)r * 64;

    float acc[64];
#pragma unroll
    for (int j = 0; j < 64; j++) acc[j] = bl[j];

    for (int k4 = 0; k4 < 64; k4 += 4) {
        float4 xv = *(const float4*)(xr + k4);
#pragma unroll
        for (int kk = 0; kk < 4; kk++) {
            float xs = (kk == 0) ? xv.x : (kk == 1) ? xv.y : (kk == 2) ? xv.z : xv.w;
#pragma unroll
            for (int j = 0; j < 64; j += 4) {
                float4 w4 = *(const float4*)&Wl[k4 + kk][j];
                acc[j + 0] += xs * w4.x;
                acc[j + 1] += xs * w4.y;
                acc[j + 2] += xs * w4.z;
                acc[j + 3] += xs * w4.w;
            }
        }
    }

    bf16* y = Y + (long)r * 64;
#pragma unroll
    for (int j = 0; j < 64; j++) {
        float v = acc[j];
        if (ACT == 2) v = fmaxf(v, 0.0f);
        else          v = (v > 0.0f) ? v : (expf(v) - 1.0f);
        y[j] = __float2bfloat16(v);
    }
}

// ---------------- fused NGCF layer + l2norm; ego bf16 updated IN PLACE --------
__global__ __launch_bounds__(256) void k_layer(const float* __restrict__ S,
                                               bf16* __restrict__ E16,
                                               const void* __restrict__ Wgc,
                                               const void* __restrict__ bgc,
                                               const void* __restrict__ Wbi,
                                               const void* __restrict__ bbi,
                                               long woff, long boff,
                                               bf16* __restrict__ nm, int M,
                                               const int* __restrict__ flag) {
    __shared__ float W1[64][64];
    __shared__ float W2[64][64];
    __shared__ float bl[64];
    int f = *flag;
    int tid = threadIdx.x;
    for (int i = tid; i < 4096; i += 256) {
        W1[i >> 6][i & 63] = ldf(Wgc, woff + i, f);
        W2[i >> 6][i & 63] = ldf(Wbi, woff + i, f);
    }
    if (tid < 64) bl[tid] = ldf(bgc, boff + tid, f) + ldf(bbi, boff + tid, f);
    __syncthreads();

    int r = blockIdx.x * 256 + tid;
    if (r >= M) return;
    const float* sr = S + (long)r * 64;
    const uint2* ep = (const uint2*)(E16 + (long)r * 64);   // 4 bf16 per uint2

    float acc[64];
#pragma unroll
    for (int j = 0; j < 64; j++) acc[j] = bl[j];

    for (int k4 = 0; k4 < 64; k4 += 4) {
        float4 sv = *(const float4*)(sr + k4);
        uint2 eq = ep[k4 >> 2];
        float e0 = __uint_as_float(eq.x << 16);
        float e1 = __uint_as_float(eq.x & 0xFFFF0000u);
        float e2 = __uint_as_float(eq.y << 16);
        float e3 = __uint_as_float(eq.y & 0xFFFF0000u);
#pragma unroll
        for (int kk = 0; kk < 4; kk++) {
            float xs = (kk == 0) ? sv.x : (kk == 1) ? sv.y : (kk == 2) ? sv.z : sv.w;
            float xe = ((kk == 0) ? e0 : (kk == 1) ? e1 : (kk == 2) ? e2 : e3) * xs;
#pragma unroll
            for (int j = 0; j < 64; j += 4) {
                float4 w1 = *(const float4*)&W1[k4 + kk][j];
                float4 w2 = *(const float4*)&W2[k4 + kk][j];
                acc[j + 0] += xs * w1.x + xe * w2.x;
                acc[j + 1] += xs * w1.y + xe * w2.y;
                acc[j + 2] += xs * w1.z + xe * w2.z;
                acc[j + 3] += xs * w1.w + xe * w2.w;
            }
        }
    }

    float ss = 0.0f;
#pragma unroll
    for (int j = 0; j < 64; j++) {
        float v = acc[j];
        v = (v > 0.0f) ? v : 0.2f * v;
        acc[j] = v;
        ss += v * v;
    }
    float sc = 1.0f / fmaxf(sqrtf(ss), 1e-12f);

    bf16* nr = nm + (long)r * 64;
    bf16* er = E16 + (long)r * 64;
#pragma unroll
    for (int j = 0; j < 64; j++) {
        er[j] = __float2bfloat16(acc[j]);
        nr[j] = __float2bfloat16(acc[j] * sc);
    }
}

// ---------------- final gather into output ----------------
__global__ __launch_bounds__(64) void k_gather(const int* __restrict__ users,
                                               const int* __restrict__ pos,
                                               const int* __restrict__ neg,
                                               const void* __restrict__ ue,
                                               const void* __restrict__ ie,
                                               const bf16* __restrict__ n1,
                                               const bf16* __restrict__ n2,
                                               const bf16* __restrict__ n3,
                                               const bf16* __restrict__ uh,
                                               const bf16* __restrict__ ih,
                                               void* __restrict__ out,
                                               const int* __restrict__ flag) {
    int f = *flag;
    int b = blockIdx.x;           // 0..12287: [users | pos | neg] x 4096
    int which = b >> 12;
    int s = b & 4095;
    int lane = threadIdx.x;       // 64
    long ebase, nbase;
    const void* e0;
    const bf16* hh;
    if (which == 0) {
        int r = users[s];
        e0 = ue; ebase = (long)r * 64;
        hh = uh + (long)r * 64;
        nbase = (long)r * 64;
    } else {
        int r = (which == 1) ? pos[s] : neg[s];
        e0 = ie; ebase = (long)r * 64;
        hh = ih + (long)r * 64;
        nbase = (long)(N_USER + r) * 64;
    }
    float o0 = ldf(e0, ebase + lane, f);
    float o1 = __bfloat162float(n1[nbase + lane]);
    float o2 = __bfloat162float(n2[nbase + lane]);
    float o3 = __bfloat162float(n3[nbase + lane]);
    float o4 = __bfloat162float(hh[lane]);
    long ob = (long)b * 320;
    if (f) {
        float* o = (float*)out + ob;
        o[lane] = o0; o[64 + lane] = o1; o[128 + lane] = o2;
        o[192 + lane] = o3; o[256 + lane] = o4;
    } else {
        bf16* o = (bf16*)out + ob;
        o[lane]       = __float2bfloat16(o0);
        o[64 + lane]  = __float2bfloat16(o1);
        o[128 + lane] = __float2bfloat16(o2);
        o[192 + lane] = __float2bfloat16(o3);
        o[256 + lane] = __float2bfloat16(o4);
    }
}

// host-side helper: two-level build of row-sorted packed records for one graph
static void build_graph(const int* rows, const int* cols, const void* vals,
                        int nnz, int nsb, int cap, int n_rows,
                        int* sbpos, uint2* recTmp, uint2* rec2,
                        int* rstart, int* rend,
                        const int* FLAG, hipStream_t stream) {
    k_initpos<<<1, 256, 0, stream>>>(sbpos, nsb, cap);
    k_part<<<(nnz + CHUNK - 1) / CHUNK, 256, 0, stream>>>(rows, cols, vals, recTmp, sbpos, nnz, FLAG);
    k_sortsb<<<nsb, 1024, 0, stream>>>(recTmp, rec2, rstart, rend, sbpos, cap, n_rows);
}

extern "C" void kernel_launch(void* const* d_in, const int* in_sizes, int n_in,
                              void* d_out, int out_size, void* d_ws, size_t ws_size,
                              hipStream_t stream) {
    const int* users = (const int*)d_in[0];
    const int* pos   = (const int*)d_in[1];
    const int* neg   = (const int*)d_in[2];
    const int* adj_r = (const int*)d_in[3];
    const int* adj_c = (const int*)d_in[4];
    const void* adj_v = d_in[5];
    const int* ug_r  = (const int*)d_in[6];
    const int* ug_c  = (const int*)d_in[7];
    const void* ug_v = d_in[8];
    const int* ig_r  = (const int*)d_in[9];
    const int* ig_c  = (const int*)d_in[10];
    const void* ig_v = d_in[11];
    const void* ue   = d_in[12];
    const void* ie   = d_in[13];
    const void* Wgc  = d_in[14];
    const void* bgc  = d_in[15];
    const void* Wbi  = d_in[16];
    const void* bbi  = d_in[17];
    const void* Wu0  = d_in[18];
    const void* bu0  = d_in[19];
    const void* Wu1  = d_in[20];
    const void* bu1  = d_in[21];
    const void* Wi0  = d_in[22];
    const void* bi0  = d_in[23];
    const void* Wi1  = d_in[24];
    const void* bi1  = d_in[25];

    char* ws = (char*)d_ws;
    int*   FLAG  = (int*)(ws + 0);                       // 256 B
    float* T1    = (float*)(ws + 256);                   // 46,080,000 (fp32 NTOT*64)
    bf16*  ego16 = (bf16*)(ws + 46080256L);              // 23,040,000
    bf16*  UH    = (bf16*)(ws + 69120256L);              //  7,680,000
    bf16*  IH    = (bf16*)(ws + 76800256L);              // 15,360,000
    bf16*  NM1   = (bf16*)(ws + 92160256L);              // 23,040,000
    bf16*  NM2   = (bf16*)(ws + 115200256L);             // 23,040,000
    bf16*  NM3   = (bf16*)(ws + 138240256L);             // 23,040,000
    // T2 (bf16, <=15.36 MB) aliases NM2 region: dead before layer k=1 writes NM2
    bf16*  T2    = (bf16*)(ws + 115200256L);
    // recTmp aliases T1: builds finish before any SpMM writes T1 (adj needs 30.3 MB < 46 MB)
    uint2* recTmp = (uint2*)(ws + 256);
    uint2* rec2A = (uint2*)(ws + 161280256L);            // 88*43008*8 = 30,277,632
    uint2* rec2U = (uint2*)(ws + 191557888L);            // 30*34816*8 =  8,355,840
    uint2* rec2I = (uint2*)(ws + 199913728L);            // 59*34816*8 = 16,433,152
    int* rstartA = (int*)(ws + 216346880L);              //    720,000
    int* rendA   = (int*)(ws + 217066880L);              //    720,000
    int* rstartU = (int*)(ws + 217786880L);              //    240,000
    int* rendU   = (int*)(ws + 218026880L);              //    240,000
    int* rstartI = (int*)(ws + 218266880L);              //    480,000
    int* rendI   = (int*)(ws + 218746880L);              //    480,000
    int* sbpos   = (int*)(ws + 219226880L);              //      6,144 (96 x 64B lines)
                                                         // end 219,233,024 (< 261,120,256 proven)

    k_detect<<<1, 64, 0, stream>>>(adj_v, FLAG);
    k_cast16<<<45000, 256, 0, stream>>>(ue, ie, ego16, FLAG);

    // ---- two-level build of row-sorted packed records (recTmp aliases T1) ----
    build_graph(ug_r,  ug_c,  ug_v,  NNZ_UG,  NSB_UG,  CAPU_SB, N_USER,
                sbpos, recTmp, rec2U, rstartU, rendU, FLAG, stream);
    build_graph(ig_r,  ig_c,  ig_v,  NNZ_IG,  NSB_IG,  CAPI_SB, N_ITEM,
                sbpos, recTmp, rec2I, rstartI, rendI, FLAG, stream);
    build_graph(adj_r, adj_c, adj_v, NNZ_ADJ, NSB_ADJ, CAPA_SB, NTOT,
                sbpos, recTmp, rec2A, rstartA, rendA, FLAG, stream);

    // ---- user MLP branch ----
    k_spmm_bf<<<(N_USER + 31) / 32, 256, 0, stream>>>(rstartU, rendU, rec2U, ego16, T1, N_USER);
    k_gemm64<1><<<(N_USER + 255) / 256, 256, 0, stream>>>(T1, Wu0, bu0, T2, N_USER, FLAG);
    k_spmm_bf<<<(N_USER + 31) / 32, 256, 0, stream>>>(rstartU, rendU, rec2U, T2, T1, N_USER);
    k_gemm64<2><<<(N_USER + 255) / 256, 256, 0, stream>>>(T1, Wu1, bu1, UH, N_USER, FLAG);

    // ---- item MLP branch ----
    const bf16* ego16I = ego16 + (size_t)N_USER * 64;
    k_spmm_bf<<<(N_ITEM + 31) / 32, 256, 0, stream>>>(rstartI, rendI, rec2I, ego16I, T1, N_ITEM);
    k_gemm64<1><<<(N_ITEM + 255) / 256, 256, 0, stream>>>(T1, Wi0, bi0, T2, N_ITEM, FLAG);
    k_spmm_bf<<<(N_ITEM + 31) / 32, 256, 0, stream>>>(rstartI, rendI, rec2I, T2, T1, N_ITEM);
    k_gemm64<2><<<(N_ITEM + 255) / 256, 256, 0, stream>>>(T1, Wi1, bi1, IH, N_ITEM, FLAG);

    // ---- 3 NGCF layers (ego bf16 in place; norm fused) ----
    bf16* norms[3] = {NM1, NM2, NM3};
    for (int k = 0; k < 3; k++) {
        k_spmm_bf<<<(NTOT + 31) / 32, 256, 0, stream>>>(rstartA, rendA, rec2A, ego16, T1, NTOT);
        k_layer<<<(NTOT + 255) / 256, 256, 0, stream>>>(T1, ego16, Wgc, bgc, Wbi, bbi,
                                                        (long)k * 4096, (long)k * 64,
                                                        norms[k], NTOT, FLAG);
    }

    // ---- output gather ----
    k_gather<<<12288, 64, 0, stream>>>(users, pos, neg, ue, ie, NM1, NM2, NM3, UH, IH,
                                       d_out, FLAG);
}